// Round 2
// baseline (972.431 us; speedup 1.0000x reference)
//
#include <hip/hip_runtime.h>

#define NT   8      // dense points per block
#define KNN  16     // neighbors
#define CIN  128
#define CF   160    // Cin + PE
#define MM   16     // weightnet out channels
#define PEC  32     // positional encoding channels
#define COUT 128
#define LEPS 1e-5f

__device__ __forceinline__ float bf2f(unsigned short b){
  union { unsigned int u; float f; } x; x.u = ((unsigned int)b) << 16; return x.f;
}
__device__ __forceinline__ unsigned short f2bf(float f){
  union { float f; unsigned int u; } x; x.f = f;
  unsigned int r = (x.u + 0x7fffu + ((x.u >> 16) & 1u)) >> 16;
  return (unsigned short)r;
}
__device__ __forceinline__ float rsum16(float v){
  v += __shfl_xor(v, 8, 16);
  v += __shfl_xor(v, 4, 16);
  v += __shfl_xor(v, 2, 16);
  v += __shfl_xor(v, 1, 16);
  return v;
}
__device__ __forceinline__ float rsum32(float v){
  v += __shfl_xor(v, 16, 32);
  v += __shfl_xor(v, 8, 32);
  v += __shfl_xor(v, 4, 32);
  v += __shfl_xor(v, 2, 32);
  v += __shfl_xor(v, 1, 32);
  return v;
}
__device__ __forceinline__ float lrelu(float v){ return v >= 0.f ? v : 0.1f * v; }

__global__ __launch_bounds__(256)
void pct_kernel(
    const float* __restrict__ sparse_xyz,
    const float* __restrict__ sparse_feats,
    const int* __restrict__ nei_inds,
    const float* __restrict__ dense_xyz,
    const float* __restrict__ dense_feats,
    const float* __restrict__ pe_w0, const float* __restrict__ pe_b0,
    const float* __restrict__ pe_g0, const float* __restrict__ pe_be0,
    const float* __restrict__ pe_w1, const float* __restrict__ pe_b1,
    const float* __restrict__ pe_g1, const float* __restrict__ pe_be1,
    const float* __restrict__ wn_w0, const float* __restrict__ wn_b0,
    const float* __restrict__ wn_g0, const float* __restrict__ wn_be0,
    const float* __restrict__ wn_w1, const float* __restrict__ wn_b1,
    const float* __restrict__ wn_g1, const float* __restrict__ wn_be1,
    const float* __restrict__ wn_w2, const float* __restrict__ wn_b2,
    const float* __restrict__ wn_g2, const float* __restrict__ wn_be2,
    const float* __restrict__ lin_w, const float* __restrict__ lin_b,
    const float* __restrict__ lin_g, const float* __restrict__ lin_be,
    float* __restrict__ out)
{
  __shared__ __align__(16) unsigned short feat_s[KNN][CF];   // 5120 B (bf16 bits)
  __shared__ float wts_s[KNN][MM];                            // 1024 B
  __shared__ float loc_s[KNN][3];                             // 192 B
  __shared__ int   nei_s[KNN];                                // 64 B
  __shared__ __align__(16) unsigned short out_tile[CF*MM][NT];// 40960 B, [i][p]

  const int t  = threadIdx.x;
  const int n0 = blockIdx.x * NT;
  const int k  = t >> 4;   // neighbor group 0..15
  const int l  = t & 15;   // lane within group

#pragma unroll 1
  for (int p = 0; p < NT; ++p) {
    const int n = n0 + p;
    if (t < KNN) {
      int idx = nei_inds[n*KNN + t];
      nei_s[t] = idx;
      loc_s[t][0] = sparse_xyz[idx*3+0] - dense_xyz[n*3+0];
      loc_s[t][1] = sparse_xyz[idx*3+1] - dense_xyz[n*3+1];
      loc_s[t][2] = sparse_xyz[idx*3+2] - dense_xyz[n*3+2];
    }
    __syncthreads();

    // stage gathered features: 8 floats per thread cover 16x128, convert to bf16
    {
      const int gk = t >> 4;
      const int c8 = (t & 15) * 8;
      const float* src = sparse_feats + (long)nei_s[gk]*CIN + c8;
      const float4 va = *(const float4*)(src);
      const float4 vb = *(const float4*)(src + 4);
      unsigned short* dst = &feat_s[gk][c8];
      dst[0] = f2bf(va.x); dst[1] = f2bf(va.y); dst[2] = f2bf(va.z); dst[3] = f2bf(va.w);
      dst[4] = f2bf(vb.x); dst[5] = f2bf(vb.y); dst[6] = f2bf(vb.z); dst[7] = f2bf(vb.w);
    }

    // ---- small nets: all in registers + width-16 shuffles ----
    const float x0 = loc_s[k][0], x1 = loc_s[k][1], x2 = loc_s[k][2];

    // pe layer0 (3->32), LN, LeakyReLU; lane handles c0=l and c1=l+16
    const int c0 = l, c1 = l + 16;
    float ha = x0*pe_w0[0*PEC+c0] + x1*pe_w0[1*PEC+c0] + x2*pe_w0[2*PEC+c0] + pe_b0[c0];
    float hb = x0*pe_w0[0*PEC+c1] + x1*pe_w0[1*PEC+c1] + x2*pe_w0[2*PEC+c1] + pe_b0[c1];
    {
      float mu = rsum16(ha + hb) * (1.f/32.f);
      float da = ha - mu, db = hb - mu;
      float q  = rsum16(da*da + db*db);
      float rs = rsqrtf(q*(1.f/32.f) + LEPS);
      ha = lrelu(da*rs*pe_g0[c0] + pe_be0[c0]);
      hb = lrelu(db*rs*pe_g0[c1] + pe_be0[c1]);
    }
    // pe layer1 (32->32) via shfl all-gather, LN (no act)
    float za = pe_b1[c0], zb = pe_b1[c1];
#pragma unroll
    for (int j = 0; j < 16; ++j) {
      float va = __shfl(ha, j, 16);
      float vb = __shfl(hb, j, 16);
      za += va * pe_w1[j*PEC + c0] + vb * pe_w1[(j+16)*PEC + c0];
      zb += va * pe_w1[j*PEC + c1] + vb * pe_w1[(j+16)*PEC + c1];
    }
    {
      float mu = rsum16(za + zb) * (1.f/32.f);
      float da = za - mu, db = zb - mu;
      float q  = rsum16(da*da + db*db);
      float rs = rsqrtf(q*(1.f/32.f) + LEPS);
      feat_s[k][CIN + c0] = f2bf(da*rs*pe_g1[c0] + pe_be1[c0]);
      feat_s[k][CIN + c1] = f2bf(db*rs*pe_g1[c1] + pe_be1[c1]);
    }

    // wn layer0 (3->16), LN, act
    float w0v = x0*wn_w0[0*MM+l] + x1*wn_w0[1*MM+l] + x2*wn_w0[2*MM+l] + wn_b0[l];
    {
      float mu = rsum16(w0v) * (1.f/16.f);
      float d  = w0v - mu;
      float rs = rsqrtf(rsum16(d*d)*(1.f/16.f) + LEPS);
      w0v = lrelu(d*rs*wn_g0[l] + wn_be0[l]);
    }
    // wn layer1 (16->16), LN, act
    float w1v = wn_b1[l];
#pragma unroll
    for (int j = 0; j < 16; ++j)
      w1v += __shfl(w0v, j, 16) * wn_w1[j*MM + l];
    {
      float mu = rsum16(w1v) * (1.f/16.f);
      float d  = w1v - mu;
      float rs = rsqrtf(rsum16(d*d)*(1.f/16.f) + LEPS);
      w1v = lrelu(d*rs*wn_g1[l] + wn_be1[l]);
    }
    // wn layer2 (16->16), LN, no act
    float w2v = wn_b2[l];
#pragma unroll
    for (int j = 0; j < 16; ++j)
      w2v += __shfl(w1v, j, 16) * wn_w2[j*MM + l];
    {
      float mu = rsum16(w2v) * (1.f/16.f);
      float d  = w2v - mu;
      float rs = rsqrtf(rsum16(d*d)*(1.f/16.f) + LEPS);
      w2v = d*rs*wn_g2[l] + wn_be2[l];
    }
    wts_s[k][l] = w2v;
    __syncthreads();

    // ---- einsum: out[c*16+m] = sum_k feat[k][c] * wts[k][m] ----
    {
      const int m = t & 15;
      const int g = t >> 4;  // 0..15, covers c = g*10+j
      float wv[KNN];
#pragma unroll
      for (int kk = 0; kk < KNN; ++kk) wv[kk] = wts_s[kk][m];
#pragma unroll
      for (int j = 0; j < 10; ++j) {
        const int c = g*10 + j;
        float acc = 0.f;
#pragma unroll
        for (int kk = 0; kk < KNN; ++kk)
          acc += bf2f(feat_s[kk][c]) * wv[kk];
        out_tile[c*MM + m][p] = f2bf(acc);
      }
    }
    __syncthreads();
  }

  // ---- final linear 2560->128 (+bias, LN, LeakyReLU, +dense_feats) ----
  {
    const int h  = t >> 6;          // i-range split 0..3
    const int o0 = (t & 63) * 2;    // even output channel
    float acc0[NT], acc1[NT];
#pragma unroll
    for (int p = 0; p < NT; ++p) { acc0[p] = 0.f; acc1[p] = 0.f; }
    const int i0 = h * 640;
    for (int i = i0; i < i0 + 640; ++i) {
      const float2 wv = *(const float2*)(lin_w + (long)i*COUT + o0);
      const float wa = wv.x;
      const float wc = wv.y;
      const uint4 r = *(const uint4*)(&out_tile[i][0]);
      const float f0 = bf2f((unsigned short)(r.x & 0xffffu));
      const float f1 = bf2f((unsigned short)(r.x >> 16));
      const float g2 = bf2f((unsigned short)(r.y & 0xffffu));
      const float g3 = bf2f((unsigned short)(r.y >> 16));
      const float g4 = bf2f((unsigned short)(r.z & 0xffffu));
      const float g5 = bf2f((unsigned short)(r.z >> 16));
      const float g6 = bf2f((unsigned short)(r.w & 0xffffu));
      const float g7 = bf2f((unsigned short)(r.w >> 16));
      acc0[0] += f0*wa; acc1[0] += f0*wc;
      acc0[1] += f1*wa; acc1[1] += f1*wc;
      acc0[2] += g2*wa; acc1[2] += g2*wc;
      acc0[3] += g3*wa; acc1[3] += g3*wc;
      acc0[4] += g4*wa; acc1[4] += g4*wc;
      acc0[5] += g5*wa; acc1[5] += g5*wc;
      acc0[6] += g6*wa; acc1[6] += g6*wc;
      acc0[7] += g7*wa; acc1[7] += g7*wc;
    }
    __syncthreads();                       // all out_tile reads done
    float* red = (float*)&out_tile[0][0];  // alias 16 KB of the 40 KB tile
#pragma unroll
    for (int p = 0; p < NT; ++p) {
      red[((h*NT + p) << 7) + o0    ] = acc0[p];
      red[((h*NT + p) << 7) + o0 + 1] = acc1[p];
    }
    __syncthreads();

    const int p2 = t >> 5, l2 = t & 31;
    const int n  = n0 + p2;
    float v[4];
#pragma unroll
    for (int j = 0; j < 4; ++j) {
      const int o = l2 + (j << 5);
      float sv = red[((0*NT + p2) << 7) + o] + red[((1*NT + p2) << 7) + o]
               + red[((2*NT + p2) << 7) + o] + red[((3*NT + p2) << 7) + o];
      v[j] = sv + lin_b[o];
    }
    float mu = rsum32(v[0] + v[1] + v[2] + v[3]) * (1.f/128.f);
    float q = 0.f;
#pragma unroll
    for (int j = 0; j < 4; ++j) { float d = v[j] - mu; q += d*d; }
    float rs = rsqrtf(rsum32(q) * (1.f/128.f) + LEPS);
#pragma unroll
    for (int j = 0; j < 4; ++j) {
      const int o = l2 + (j << 5);
      float y = (v[j] - mu) * rs * lin_g[o] + lin_be[o];
      y = lrelu(y);
      y += dense_feats[n*COUT + o];
      out[n*COUT + o] = y;
    }
  }
}

extern "C" void kernel_launch(void* const* d_in, const int* in_sizes, int n_in,
                              void* d_out, int out_size, void* d_ws, size_t ws_size,
                              hipStream_t stream) {
  const int Nd = in_sizes[2] / KNN;   // 40000
  dim3 grid(Nd / NT);                  // 5000 blocks (Nd divisible by NT)
  pct_kernel<<<grid, dim3(256), 0, stream>>>(
    (const float*)d_in[0],  (const float*)d_in[1],  (const int*)d_in[2],
    (const float*)d_in[4],  (const float*)d_in[6],
    (const float*)d_in[7],  (const float*)d_in[8],  (const float*)d_in[9],  (const float*)d_in[10],
    (const float*)d_in[11], (const float*)d_in[12], (const float*)d_in[13], (const float*)d_in[14],
    (const float*)d_in[15], (const float*)d_in[16], (const float*)d_in[17], (const float*)d_in[18],
    (const float*)d_in[19], (const float*)d_in[20], (const float*)d_in[21], (const float*)d_in[22],
    (const float*)d_in[23], (const float*)d_in[24], (const float*)d_in[25], (const float*)d_in[26],
    (const float*)d_in[27], (const float*)d_in[28], (const float*)d_in[29], (const float*)d_in[30],
    (float*)d_out);
}

// Round 3
// 641.163 us; speedup vs baseline: 1.5167x; 1.5167x over previous
//
#include <hip/hip_runtime.h>

#define NT   8      // dense points per block (phase A)
#define KNN  16     // neighbors
#define CIN  128
#define CF   160    // Cin + PE
#define MM   16     // weightnet out channels
#define PEC  32     // positional encoding channels
#define COUT 128
#define KDIM 2560   // CF * MM
#define LEPS 1e-5f

typedef __bf16 bf16x8 __attribute__((ext_vector_type(8)));
typedef float  f32x4  __attribute__((ext_vector_type(4)));
union U16x8 { uint4 u4; bf16x8 b; };

__device__ __forceinline__ float bf2f(unsigned short b){
  union { unsigned int u; float f; } x; x.u = ((unsigned int)b) << 16; return x.f;
}
__device__ __forceinline__ unsigned short f2bf(float f){
  union { float f; unsigned int u; } x; x.f = f;
  unsigned int r = (x.u + 0x7fffu + ((x.u >> 16) & 1u)) >> 16;
  return (unsigned short)r;
}
__device__ __forceinline__ float rsum16(float v){
  v += __shfl_xor(v, 8, 16);
  v += __shfl_xor(v, 4, 16);
  v += __shfl_xor(v, 2, 16);
  v += __shfl_xor(v, 1, 16);
  return v;
}
__device__ __forceinline__ float rsum8(float v){
  v += __shfl_xor(v, 4, 8);
  v += __shfl_xor(v, 2, 8);
  v += __shfl_xor(v, 1, 8);
  return v;
}
__device__ __forceinline__ float rsum32(float v){
  v += __shfl_xor(v, 16, 32);
  v += __shfl_xor(v, 8, 32);
  v += __shfl_xor(v, 4, 32);
  v += __shfl_xor(v, 2, 32);
  v += __shfl_xor(v, 1, 32);
  return v;
}
__device__ __forceinline__ float lrelu(float v){ return v >= 0.f ? v : 0.1f * v; }

// ============================================================================
// Kernel P: pack lin_w (f32 [2560][128]) -> bf16 B-fragment-linear layout.
// Element (s, tt, lane, j): k = s*32 + (lane>>4)*8 + j, n = tt*16 + (lane&15)
// stored at wpack[((s*8 + tt)*64 + lane)*8 + j]. 80*8*64 threads, 8 elems each.
// ============================================================================
__global__ __launch_bounds__(256)
void pct_pack_w(const float* __restrict__ lin_w, unsigned short* __restrict__ wpack)
{
  const int u    = blockIdx.x * 256 + threadIdx.x;   // 0..40959
  const int lane = u & 63;
  const int tt   = (u >> 6) & 7;
  const int s    = u >> 9;
  const int kb   = s * 32 + ((lane >> 4) * 8);
  const int n    = tt * 16 + (lane & 15);
  unsigned short v[8];
#pragma unroll
  for (int j = 0; j < 8; ++j)
    v[j] = f2bf(lin_w[(long)(kb + j) * COUT + n]);
  *(uint4*)(wpack + (long)u * 8) = *(uint4*)v;
}

// ============================================================================
// Kernel A: gather + small nets + einsum -> apack[n][i] bf16 (i = c*16 + m)
// ============================================================================
__global__ __launch_bounds__(256)
void pct_phase_a(
    const float* __restrict__ sparse_xyz,
    const float* __restrict__ sparse_feats,
    const int* __restrict__ nei_inds,
    const float* __restrict__ dense_xyz,
    const float* __restrict__ pe_w0, const float* __restrict__ pe_b0,
    const float* __restrict__ pe_g0, const float* __restrict__ pe_be0,
    const float* __restrict__ pe_w1, const float* __restrict__ pe_b1,
    const float* __restrict__ pe_g1, const float* __restrict__ pe_be1,
    const float* __restrict__ wn_w0, const float* __restrict__ wn_b0,
    const float* __restrict__ wn_g0, const float* __restrict__ wn_be0,
    const float* __restrict__ wn_w1, const float* __restrict__ wn_b1,
    const float* __restrict__ wn_g1, const float* __restrict__ wn_be1,
    const float* __restrict__ wn_w2, const float* __restrict__ wn_b2,
    const float* __restrict__ wn_g2, const float* __restrict__ wn_be2,
    unsigned short* __restrict__ apack)
{
  __shared__ __align__(16) unsigned short feat_s[KNN][CF];   // 5120 B
  __shared__ float wts_s[KNN][MM];
  __shared__ float loc_s[KNN][3];
  __shared__ int   nei_s[KNN];

  const int t  = threadIdx.x;
  const int n0 = blockIdx.x * NT;
  const int k  = t >> 4;   // neighbor group 0..15
  const int l  = t & 15;   // lane within group

#pragma unroll 1
  for (int p = 0; p < NT; ++p) {
    const int n = n0 + p;
    if (t < KNN) {
      int idx = nei_inds[n*KNN + t];
      nei_s[t] = idx;
      loc_s[t][0] = sparse_xyz[idx*3+0] - dense_xyz[n*3+0];
      loc_s[t][1] = sparse_xyz[idx*3+1] - dense_xyz[n*3+1];
      loc_s[t][2] = sparse_xyz[idx*3+2] - dense_xyz[n*3+2];
    }
    __syncthreads();

    // stage gathered features: 8 floats per thread cover 16x128, convert to bf16
    {
      const int gk = t >> 4;
      const int c8 = (t & 15) * 8;
      const float* src = sparse_feats + (long)nei_s[gk]*CIN + c8;
      const float4 va = *(const float4*)(src);
      const float4 vb = *(const float4*)(src + 4);
      unsigned short* dst = &feat_s[gk][c8];
      dst[0] = f2bf(va.x); dst[1] = f2bf(va.y); dst[2] = f2bf(va.z); dst[3] = f2bf(va.w);
      dst[4] = f2bf(vb.x); dst[5] = f2bf(vb.y); dst[6] = f2bf(vb.z); dst[7] = f2bf(vb.w);
    }

    // ---- small nets ----
    const float x0 = loc_s[k][0], x1 = loc_s[k][1], x2 = loc_s[k][2];

    const int c0 = l, c1 = l + 16;
    float ha = x0*pe_w0[0*PEC+c0] + x1*pe_w0[1*PEC+c0] + x2*pe_w0[2*PEC+c0] + pe_b0[c0];
    float hb = x0*pe_w0[0*PEC+c1] + x1*pe_w0[1*PEC+c1] + x2*pe_w0[2*PEC+c1] + pe_b0[c1];
    {
      float mu = rsum16(ha + hb) * (1.f/32.f);
      float da = ha - mu, db = hb - mu;
      float q  = rsum16(da*da + db*db);
      float rs = rsqrtf(q*(1.f/32.f) + LEPS);
      ha = lrelu(da*rs*pe_g0[c0] + pe_be0[c0]);
      hb = lrelu(db*rs*pe_g0[c1] + pe_be0[c1]);
    }
    float za = pe_b1[c0], zb = pe_b1[c1];
#pragma unroll
    for (int j = 0; j < 16; ++j) {
      float va = __shfl(ha, j, 16);
      float vb = __shfl(hb, j, 16);
      za += va * pe_w1[j*PEC + c0] + vb * pe_w1[(j+16)*PEC + c0];
      zb += va * pe_w1[j*PEC + c1] + vb * pe_w1[(j+16)*PEC + c1];
    }
    {
      float mu = rsum16(za + zb) * (1.f/32.f);
      float da = za - mu, db = zb - mu;
      float q  = rsum16(da*da + db*db);
      float rs = rsqrtf(q*(1.f/32.f) + LEPS);
      feat_s[k][CIN + c0] = f2bf(da*rs*pe_g1[c0] + pe_be1[c0]);
      feat_s[k][CIN + c1] = f2bf(db*rs*pe_g1[c1] + pe_be1[c1]);
    }

    float w0v = x0*wn_w0[0*MM+l] + x1*wn_w0[1*MM+l] + x2*wn_w0[2*MM+l] + wn_b0[l];
    {
      float mu = rsum16(w0v) * (1.f/16.f);
      float d  = w0v - mu;
      float rs = rsqrtf(rsum16(d*d)*(1.f/16.f) + LEPS);
      w0v = lrelu(d*rs*wn_g0[l] + wn_be0[l]);
    }
    float w1v = wn_b1[l];
#pragma unroll
    for (int j = 0; j < 16; ++j)
      w1v += __shfl(w0v, j, 16) * wn_w1[j*MM + l];
    {
      float mu = rsum16(w1v) * (1.f/16.f);
      float d  = w1v - mu;
      float rs = rsqrtf(rsum16(d*d)*(1.f/16.f) + LEPS);
      w1v = lrelu(d*rs*wn_g1[l] + wn_be1[l]);
    }
    float w2v = wn_b2[l];
#pragma unroll
    for (int j = 0; j < 16; ++j)
      w2v += __shfl(w1v, j, 16) * wn_w2[j*MM + l];
    {
      float mu = rsum16(w2v) * (1.f/16.f);
      float d  = w2v - mu;
      float rs = rsqrtf(rsum16(d*d)*(1.f/16.f) + LEPS);
      w2v = d*rs*wn_g2[l] + wn_be2[l];
    }
    wts_s[k][l] = w2v;
    __syncthreads();

    // ---- einsum -> global apack[n][i], i = t + 256*jj (coalesced bf16) ----
    {
      const int m = t & 15;
      float wv[KNN];
#pragma unroll
      for (int kk = 0; kk < KNN; ++kk) wv[kk] = wts_s[kk][m];
      unsigned short* dst = apack + (long)n * KDIM;
#pragma unroll
      for (int jj = 0; jj < 10; ++jj) {
        const int c = (t >> 4) + 16*jj;
        float acc = 0.f;
#pragma unroll
        for (int kk = 0; kk < KNN; ++kk)
          acc += bf2f(feat_s[kk][c]) * wv[kk];
        dst[jj*256 + t] = f2bf(acc);
      }
    }
    __syncthreads();
  }
}

// ============================================================================
// Kernel B: C[40000x128] = A[40000x2560](bf16) @ W[2560x128](bf16 frag-packed)
// then bias + LN + LeakyReLU + residual. 32 points/block, 4 waves.
// Wave w: mt = w>>1 (16-point tile), nh = w&1 (64-col half, 4 n-tiles).
// ============================================================================
__global__ __launch_bounds__(256)
void pct_gemm(
    const unsigned short* __restrict__ apack,
    const unsigned short* __restrict__ wpack,
    const float* __restrict__ lin_b, const float* __restrict__ lin_g,
    const float* __restrict__ lin_be, const float* __restrict__ dense_feats,
    float* __restrict__ out)
{
  __shared__ float out_s[32][132];   // padded row: conflict-free scatter

  const int t    = threadIdx.x;
  const int wave = t >> 6;
  const int lane = t & 63;
  const int mt   = wave >> 1;
  const int nh   = wave & 1;
  const int n0   = blockIdx.x * 32;

  const unsigned short* arow = apack + (long)(n0 + mt*16 + (lane & 15)) * KDIM
                                     + ((lane >> 4) * 8);
  const unsigned short* wrow = wpack + ((long)(nh*4) * 64 + lane) * 8;

  f32x4 acc0 = {0.f,0.f,0.f,0.f}, acc1 = {0.f,0.f,0.f,0.f};
  f32x4 acc2 = {0.f,0.f,0.f,0.f}, acc3 = {0.f,0.f,0.f,0.f};

#pragma unroll 2
  for (int s = 0; s < 80; ++s) {
    U16x8 a;  a.u4 = *(const uint4*)(arow + s*32);
    const unsigned short* wp = wrow + (long)s * (8*64*8);
    U16x8 b0, b1, b2, b3;
    b0.u4 = *(const uint4*)(wp + 0*512);
    b1.u4 = *(const uint4*)(wp + 1*512);
    b2.u4 = *(const uint4*)(wp + 2*512);
    b3.u4 = *(const uint4*)(wp + 3*512);
    acc0 = __builtin_amdgcn_mfma_f32_16x16x32_bf16(a.b, b0.b, acc0, 0, 0, 0);
    acc1 = __builtin_amdgcn_mfma_f32_16x16x32_bf16(a.b, b1.b, acc1, 0, 0, 0);
    acc2 = __builtin_amdgcn_mfma_f32_16x16x32_bf16(a.b, b2.b, acc2, 0, 0, 0);
    acc3 = __builtin_amdgcn_mfma_f32_16x16x32_bf16(a.b, b3.b, acc3, 0, 0, 0);
  }

  // scatter C to LDS: row = mt*16 + quad*4 + r (point), col = nh*64 + tt*16 + (lane&15)
  {
    const int row0 = mt*16 + (lane >> 4)*4;
    const int col  = nh*64 + (lane & 15);
#pragma unroll
    for (int r = 0; r < 4; ++r) {
      out_s[row0 + r][col +  0] = acc0[r];
      out_s[row0 + r][col + 16] = acc1[r];
      out_s[row0 + r][col + 32] = acc2[r];
      out_s[row0 + r][col + 48] = acc3[r];
    }
  }
  __syncthreads();

  // LN + LeakyReLU + residual; 8 threads per point, 16 cols each
  {
    const int p  = t >> 3;
    const int l8 = t & 7;
    const int n  = n0 + p;
    const int cb = l8 * 16;
    float v[16];
#pragma unroll
    for (int q = 0; q < 16; q += 4) {
      float4 r = *(const float4*)(&out_s[p][cb + q]);
      float4 bb = *(const float4*)(lin_b + cb + q);
      v[q+0] = r.x + bb.x; v[q+1] = r.y + bb.y; v[q+2] = r.z + bb.z; v[q+3] = r.w + bb.w;
    }
    float sum = 0.f;
#pragma unroll
    for (int q = 0; q < 16; ++q) sum += v[q];
    float mu = rsum8(sum) * (1.f/128.f);
    float qs = 0.f;
#pragma unroll
    for (int q = 0; q < 16; ++q) { float d = v[q] - mu; qs += d*d; }
    float rs = rsqrtf(rsum8(qs) * (1.f/128.f) + LEPS);
#pragma unroll
    for (int q = 0; q < 16; q += 4) {
      float4 g  = *(const float4*)(lin_g  + cb + q);
      float4 be = *(const float4*)(lin_be + cb + q);
      float4 df = *(const float4*)(dense_feats + (long)n*COUT + cb + q);
      float4 y;
      y.x = lrelu((v[q+0]-mu)*rs*g.x + be.x) + df.x;
      y.y = lrelu((v[q+1]-mu)*rs*g.y + be.y) + df.y;
      y.z = lrelu((v[q+2]-mu)*rs*g.z + be.z) + df.z;
      y.w = lrelu((v[q+3]-mu)*rs*g.w + be.w) + df.w;
      *(float4*)(out + (long)n*COUT + cb + q) = y;
    }
  }
}

// ============================================================================
// Fallback: round-2 fully-fused kernel (used if ws_size is too small)
// ============================================================================
__global__ __launch_bounds__(256)
void pct_fused(
    const float* __restrict__ sparse_xyz,
    const float* __restrict__ sparse_feats,
    const int* __restrict__ nei_inds,
    const float* __restrict__ dense_xyz,
    const float* __restrict__ dense_feats,
    const float* __restrict__ pe_w0, const float* __restrict__ pe_b0,
    const float* __restrict__ pe_g0, const float* __restrict__ pe_be0,
    const float* __restrict__ pe_w1, const float* __restrict__ pe_b1,
    const float* __restrict__ pe_g1, const float* __restrict__ pe_be1,
    const float* __restrict__ wn_w0, const float* __restrict__ wn_b0,
    const float* __restrict__ wn_g0, const float* __restrict__ wn_be0,
    const float* __restrict__ wn_w1, const float* __restrict__ wn_b1,
    const float* __restrict__ wn_g1, const float* __restrict__ wn_be1,
    const float* __restrict__ wn_w2, const float* __restrict__ wn_b2,
    const float* __restrict__ wn_g2, const float* __restrict__ wn_be2,
    const float* __restrict__ lin_w, const float* __restrict__ lin_b,
    const float* __restrict__ lin_g, const float* __restrict__ lin_be,
    float* __restrict__ out)
{
  __shared__ __align__(16) unsigned short feat_s[KNN][CF];
  __shared__ float wts_s[KNN][MM];
  __shared__ float loc_s[KNN][3];
  __shared__ int   nei_s[KNN];
  __shared__ __align__(16) unsigned short out_tile[CF*MM][NT];

  const int t  = threadIdx.x;
  const int n0 = blockIdx.x * NT;
  const int k  = t >> 4;
  const int l  = t & 15;

#pragma unroll 1
  for (int p = 0; p < NT; ++p) {
    const int n = n0 + p;
    if (t < KNN) {
      int idx = nei_inds[n*KNN + t];
      nei_s[t] = idx;
      loc_s[t][0] = sparse_xyz[idx*3+0] - dense_xyz[n*3+0];
      loc_s[t][1] = sparse_xyz[idx*3+1] - dense_xyz[n*3+1];
      loc_s[t][2] = sparse_xyz[idx*3+2] - dense_xyz[n*3+2];
    }
    __syncthreads();
    {
      const int gk = t >> 4;
      const int c8 = (t & 15) * 8;
      const float* src = sparse_feats + (long)nei_s[gk]*CIN + c8;
      const float4 va = *(const float4*)(src);
      const float4 vb = *(const float4*)(src + 4);
      unsigned short* dst = &feat_s[gk][c8];
      dst[0] = f2bf(va.x); dst[1] = f2bf(va.y); dst[2] = f2bf(va.z); dst[3] = f2bf(va.w);
      dst[4] = f2bf(vb.x); dst[5] = f2bf(vb.y); dst[6] = f2bf(vb.z); dst[7] = f2bf(vb.w);
    }
    const float x0 = loc_s[k][0], x1 = loc_s[k][1], x2 = loc_s[k][2];
    const int c0 = l, c1 = l + 16;
    float ha = x0*pe_w0[0*PEC+c0] + x1*pe_w0[1*PEC+c0] + x2*pe_w0[2*PEC+c0] + pe_b0[c0];
    float hb = x0*pe_w0[0*PEC+c1] + x1*pe_w0[1*PEC+c1] + x2*pe_w0[2*PEC+c1] + pe_b0[c1];
    {
      float mu = rsum16(ha + hb) * (1.f/32.f);
      float da = ha - mu, db = hb - mu;
      float q  = rsum16(da*da + db*db);
      float rs = rsqrtf(q*(1.f/32.f) + LEPS);
      ha = lrelu(da*rs*pe_g0[c0] + pe_be0[c0]);
      hb = lrelu(db*rs*pe_g0[c1] + pe_be0[c1]);
    }
    float za = pe_b1[c0], zb = pe_b1[c1];
#pragma unroll
    for (int j = 0; j < 16; ++j) {
      float va = __shfl(ha, j, 16);
      float vb = __shfl(hb, j, 16);
      za += va * pe_w1[j*PEC + c0] + vb * pe_w1[(j+16)*PEC + c0];
      zb += va * pe_w1[j*PEC + c1] + vb * pe_w1[(j+16)*PEC + c1];
    }
    {
      float mu = rsum16(za + zb) * (1.f/32.f);
      float da = za - mu, db = zb - mu;
      float q  = rsum16(da*da + db*db);
      float rs = rsqrtf(q*(1.f/32.f) + LEPS);
      feat_s[k][CIN + c0] = f2bf(da*rs*pe_g1[c0] + pe_be1[c0]);
      feat_s[k][CIN + c1] = f2bf(db*rs*pe_g1[c1] + pe_be1[c1]);
    }
    float w0v = x0*wn_w0[0*MM+l] + x1*wn_w0[1*MM+l] + x2*wn_w0[2*MM+l] + wn_b0[l];
    {
      float mu = rsum16(w0v) * (1.f/16.f);
      float d  = w0v - mu;
      float rs = rsqrtf(rsum16(d*d)*(1.f/16.f) + LEPS);
      w0v = lrelu(d*rs*wn_g0[l] + wn_be0[l]);
    }
    float w1v = wn_b1[l];
#pragma unroll
    for (int j = 0; j < 16; ++j)
      w1v += __shfl(w0v, j, 16) * wn_w1[j*MM + l];
    {
      float mu = rsum16(w1v) * (1.f/16.f);
      float d  = w1v - mu;
      float rs = rsqrtf(rsum16(d*d)*(1.f/16.f) + LEPS);
      w1v = lrelu(d*rs*wn_g1[l] + wn_be1[l]);
    }
    float w2v = wn_b2[l];
#pragma unroll
    for (int j = 0; j < 16; ++j)
      w2v += __shfl(w1v, j, 16) * wn_w2[j*MM + l];
    {
      float mu = rsum16(w2v) * (1.f/16.f);
      float d  = w2v - mu;
      float rs = rsqrtf(rsum16(d*d)*(1.f/16.f) + LEPS);
      w2v = d*rs*wn_g2[l] + wn_be2[l];
    }
    wts_s[k][l] = w2v;
    __syncthreads();
    {
      const int m = t & 15;
      const int g = t >> 4;
      float wv[KNN];
#pragma unroll
      for (int kk = 0; kk < KNN; ++kk) wv[kk] = wts_s[kk][m];
#pragma unroll
      for (int j = 0; j < 10; ++j) {
        const int c = g*10 + j;
        float acc = 0.f;
#pragma unroll
        for (int kk = 0; kk < KNN; ++kk)
          acc += bf2f(feat_s[kk][c]) * wv[kk];
        out_tile[c*MM + m][p] = f2bf(acc);
      }
    }
    __syncthreads();
  }
  {
    const int h  = t >> 6;
    const int o0 = (t & 63) * 2;
    float acc0[NT], acc1[NT];
#pragma unroll
    for (int p = 0; p < NT; ++p) { acc0[p] = 0.f; acc1[p] = 0.f; }
    const int i0 = h * 640;
    for (int i = i0; i < i0 + 640; ++i) {
      const float2 wv = *(const float2*)(lin_w + (long)i*COUT + o0);
      const float wa = wv.x;
      const float wc = wv.y;
      const uint4 r = *(const uint4*)(&out_tile[i][0]);
      const float f0 = bf2f((unsigned short)(r.x & 0xffffu));
      const float f1 = bf2f((unsigned short)(r.x >> 16));
      const float g2 = bf2f((unsigned short)(r.y & 0xffffu));
      const float g3 = bf2f((unsigned short)(r.y >> 16));
      const float g4 = bf2f((unsigned short)(r.z & 0xffffu));
      const float g5 = bf2f((unsigned short)(r.z >> 16));
      const float g6 = bf2f((unsigned short)(r.w & 0xffffu));
      const float g7 = bf2f((unsigned short)(r.w >> 16));
      acc0[0] += f0*wa; acc1[0] += f0*wc;
      acc0[1] += f1*wa; acc1[1] += f1*wc;
      acc0[2] += g2*wa; acc1[2] += g2*wc;
      acc0[3] += g3*wa; acc1[3] += g3*wc;
      acc0[4] += g4*wa; acc1[4] += g4*wc;
      acc0[5] += g5*wa; acc1[5] += g5*wc;
      acc0[6] += g6*wa; acc1[6] += g6*wc;
      acc0[7] += g7*wa; acc1[7] += g7*wc;
    }
    __syncthreads();
    float* red = (float*)&out_tile[0][0];
#pragma unroll
    for (int p = 0; p < NT; ++p) {
      red[((h*NT + p) << 7) + o0    ] = acc0[p];
      red[((h*NT + p) << 7) + o0 + 1] = acc1[p];
    }
    __syncthreads();
    const int p2 = t >> 5, l2 = t & 31;
    const int n  = n0 + p2;
    float v[4];
#pragma unroll
    for (int j = 0; j < 4; ++j) {
      const int o = l2 + (j << 5);
      float sv = red[((0*NT + p2) << 7) + o] + red[((1*NT + p2) << 7) + o]
               + red[((2*NT + p2) << 7) + o] + red[((3*NT + p2) << 7) + o];
      v[j] = sv + lin_b[o];
    }
    float mu = rsum32(v[0] + v[1] + v[2] + v[3]) * (1.f/128.f);
    float q = 0.f;
#pragma unroll
    for (int j = 0; j < 4; ++j) { float d = v[j] - mu; q += d*d; }
    float rs = rsqrtf(rsum32(q) * (1.f/128.f) + LEPS);
#pragma unroll
    for (int j = 0; j < 4; ++j) {
      const int o = l2 + (j << 5);
      float y = (v[j] - mu) * rs * lin_g[o] + lin_be[o];
      y = lrelu(y);
      y += dense_feats[n*COUT + o];
      out[n*COUT + o] = y;
    }
  }
}

extern "C" void kernel_launch(void* const* d_in, const int* in_sizes, int n_in,
                              void* d_out, int out_size, void* d_ws, size_t ws_size,
                              hipStream_t stream) {
  const int Nd = in_sizes[2] / KNN;   // 40000
  const size_t a_bytes = (size_t)Nd * KDIM * 2;            // 204.8 MB
  const size_t w_bytes = (size_t)KDIM * COUT * 2;          // 655 KB
  const bool use_split = (ws_size >= a_bytes + w_bytes) && (Nd % 32 == 0);

  if (use_split) {
    unsigned short* apack = (unsigned short*)d_ws;
    unsigned short* wpack = (unsigned short*)((char*)d_ws + a_bytes);

    pct_pack_w<<<dim3((KDIM/32)*8*64/256), dim3(256), 0, stream>>>(
      (const float*)d_in[27], wpack);

    pct_phase_a<<<dim3(Nd / NT), dim3(256), 0, stream>>>(
      (const float*)d_in[0],  (const float*)d_in[1],  (const int*)d_in[2],
      (const float*)d_in[4],
      (const float*)d_in[7],  (const float*)d_in[8],  (const float*)d_in[9],  (const float*)d_in[10],
      (const float*)d_in[11], (const float*)d_in[12], (const float*)d_in[13], (const float*)d_in[14],
      (const float*)d_in[15], (const float*)d_in[16], (const float*)d_in[17], (const float*)d_in[18],
      (const float*)d_in[19], (const float*)d_in[20], (const float*)d_in[21], (const float*)d_in[22],
      (const float*)d_in[23], (const float*)d_in[24], (const float*)d_in[25], (const float*)d_in[26],
      apack);

    pct_gemm<<<dim3(Nd / 32), dim3(256), 0, stream>>>(
      apack, wpack,
      (const float*)d_in[28], (const float*)d_in[29], (const float*)d_in[30],
      (const float*)d_in[6], (float*)d_out);
  } else {
    pct_fused<<<dim3(Nd / NT), dim3(256), 0, stream>>>(
      (const float*)d_in[0],  (const float*)d_in[1],  (const int*)d_in[2],
      (const float*)d_in[4],  (const float*)d_in[6],
      (const float*)d_in[7],  (const float*)d_in[8],  (const float*)d_in[9],  (const float*)d_in[10],
      (const float*)d_in[11], (const float*)d_in[12], (const float*)d_in[13], (const float*)d_in[14],
      (const float*)d_in[15], (const float*)d_in[16], (const float*)d_in[17], (const float*)d_in[18],
      (const float*)d_in[19], (const float*)d_in[20], (const float*)d_in[21], (const float*)d_in[22],
      (const float*)d_in[23], (const float*)d_in[24], (const float*)d_in[25], (const float*)d_in[26],
      (const float*)d_in[27], (const float*)d_in[28], (const float*)d_in[29], (const float*)d_in[30],
      (float*)d_out);
  }
}

// Round 4
// 587.209 us; speedup vs baseline: 1.6560x; 1.0919x over previous
//
#include <hip/hip_runtime.h>

#define NPB  16     // dense points per block (einsum kernel)
#define KNN  16     // neighbors
#define CIN  128
#define CF   160    // Cin + PE
#define MM   16     // weightnet out channels
#define PEC  32     // positional encoding channels
#define COUT 128
#define KDIM 2560   // CF * MM
#define LEPS 1e-5f

typedef __bf16 bf16x8 __attribute__((ext_vector_type(8)));
typedef float  f32x4  __attribute__((ext_vector_type(4)));
union U16x8 { uint4 u4; bf16x8 b; unsigned short us[8]; };

// LDS weight-bank offsets (floats)
#define SW_PE_W0   0
#define SW_PE_B0   96
#define SW_PE_G0   128
#define SW_PE_BE0  160
#define SW_PE_W1   192
#define SW_PE_B1   1216
#define SW_PE_G1   1248
#define SW_PE_BE1  1280
#define SW_WN_W0   1312
#define SW_WN_B0   1360
#define SW_WN_G0   1376
#define SW_WN_BE0  1392
#define SW_WN_W1   1408
#define SW_WN_B1   1664
#define SW_WN_G1   1680
#define SW_WN_BE1  1696
#define SW_WN_W2   1712
#define SW_WN_B2   1968
#define SW_WN_G2   1984
#define SW_WN_BE2  2000
#define SW_TOTAL   2016

__device__ __forceinline__ float bf2f(unsigned short b){
  union { unsigned int u; float f; } x; x.u = ((unsigned int)b) << 16; return x.f;
}
__device__ __forceinline__ unsigned short f2bf(float f){
  union { float f; unsigned int u; } x; x.f = f;
  unsigned int r = (x.u + 0x7fffu + ((x.u >> 16) & 1u)) >> 16;
  return (unsigned short)r;
}
__device__ __forceinline__ float rsum16(float v){
  v += __shfl_xor(v, 8, 16);
  v += __shfl_xor(v, 4, 16);
  v += __shfl_xor(v, 2, 16);
  v += __shfl_xor(v, 1, 16);
  return v;
}
__device__ __forceinline__ float rsum4(float v){
  v += __shfl_xor(v, 2, 4);
  v += __shfl_xor(v, 1, 4);
  return v;
}
__device__ __forceinline__ float rsum32(float v){
  v += __shfl_xor(v, 16, 32);
  v += __shfl_xor(v, 8, 32);
  v += __shfl_xor(v, 4, 32);
  v += __shfl_xor(v, 2, 32);
  v += __shfl_xor(v, 1, 32);
  return v;
}
__device__ __forceinline__ float lrelu(float v){ return v >= 0.f ? v : 0.1f * v; }

template<int N>
__device__ __forceinline__ void ln_inlane(float* v, const float* g, const float* be, bool act){
  float mu = 0.f;
#pragma unroll
  for (int i = 0; i < N; ++i) mu += v[i];
  mu *= (1.f / N);
  float var = 0.f;
#pragma unroll
  for (int i = 0; i < N; ++i) { float d = v[i] - mu; var += d * d; }
  const float rs = rsqrtf(var * (1.f / N) + LEPS);
#pragma unroll
  for (int i = 0; i < N; ++i) {
    float y = (v[i] - mu) * rs * g[i] + be[i];
    v[i] = act ? lrelu(y) : y;
  }
}

// ============================================================================
// Kernel P: pack lin_w (f32 [2560][128]) -> bf16 B-fragment layout for the
// permuted k-index i' = chunk*128 + m*8 + j  (c = chunk*8 + j, src row c*16+m).
// Fragment (s, tt, lane, j): i' = s*32 + (lane>>4)*8 + j, n = tt*16 + (lane&15)
// stored at wpack[((s*8 + tt)*64 + lane)*8 + j].
// ============================================================================
__global__ __launch_bounds__(256)
void pct_pack_w(const float* __restrict__ lin_w, unsigned short* __restrict__ wpack)
{
  const int u    = blockIdx.x * 256 + threadIdx.x;   // 0..40959
  const int lane = u & 63;
  const int tt   = (u >> 6) & 7;
  const int s    = u >> 9;
  const int ipb  = s * 32 + ((lane >> 4) * 8);
  const int nn   = tt * 16 + (lane & 15);
  unsigned short v[8];
#pragma unroll
  for (int j = 0; j < 8; ++j) {
    const int ip    = ipb + j;
    const int chunk = ip >> 7;
    const int rem   = ip & 127;
    const int m     = rem >> 3;
    const int jc    = rem & 7;
    const int srow  = (chunk * 8 + jc) * MM + m;    // lin_w row = c*16 + m
    v[j] = f2bf(lin_w[(long)srow * COUT + nn]);
  }
  *(uint4*)(wpack + (long)u * 8) = *(uint4*)v;
}

// ============================================================================
// Kernel E: per-thread small nets (no shuffles, LN in-lane) + batched einsum.
// Block = 320 threads, 16 points. apack[n][i'], i' = chunk*128 + m*8 + j.
// ============================================================================
__global__ __launch_bounds__(320)
void pct_einsum(
    const float* __restrict__ sparse_xyz,
    const float* __restrict__ sparse_feats,
    const int* __restrict__ nei_inds,
    const float* __restrict__ dense_xyz,
    const float* __restrict__ pe_w0, const float* __restrict__ pe_b0,
    const float* __restrict__ pe_g0, const float* __restrict__ pe_be0,
    const float* __restrict__ pe_w1, const float* __restrict__ pe_b1,
    const float* __restrict__ pe_g1, const float* __restrict__ pe_be1,
    const float* __restrict__ wn_w0, const float* __restrict__ wn_b0,
    const float* __restrict__ wn_g0, const float* __restrict__ wn_be0,
    const float* __restrict__ wn_w1, const float* __restrict__ wn_b1,
    const float* __restrict__ wn_g1, const float* __restrict__ wn_be1,
    const float* __restrict__ wn_w2, const float* __restrict__ wn_b2,
    const float* __restrict__ wn_g2, const float* __restrict__ wn_be2,
    unsigned short* __restrict__ apack)
{
  __shared__ float sw[SW_TOTAL];                               // 8064 B
  __shared__ __align__(16) unsigned short feat_s[2][KNN][CIN]; // 8192 B
  __shared__ __align__(16) unsigned short pe_s[NPB][KNN][PEC]; // 16384 B
  __shared__ float wts_s[NPB][KNN*MM];                         // 16384 B

  const int t     = threadIdx.x;
  const int nbase = blockIdx.x * NPB;

  // ---- stage weights in LDS ----
  for (int i = t; i < 96;   i += 320) sw[SW_PE_W0 + i] = pe_w0[i];
  for (int i = t; i < 32;   i += 320) {
    sw[SW_PE_B0 + i] = pe_b0[i];  sw[SW_PE_G0 + i] = pe_g0[i];  sw[SW_PE_BE0 + i] = pe_be0[i];
    sw[SW_PE_B1 + i] = pe_b1[i];  sw[SW_PE_G1 + i] = pe_g1[i];  sw[SW_PE_BE1 + i] = pe_be1[i];
  }
  for (int i = t; i < 1024; i += 320) sw[SW_PE_W1 + i] = pe_w1[i];
  for (int i = t; i < 48;   i += 320) sw[SW_WN_W0 + i] = wn_w0[i];
  for (int i = t; i < 16;   i += 320) {
    sw[SW_WN_B0 + i] = wn_b0[i];  sw[SW_WN_G0 + i] = wn_g0[i];  sw[SW_WN_BE0 + i] = wn_be0[i];
    sw[SW_WN_B1 + i] = wn_b1[i];  sw[SW_WN_G1 + i] = wn_g1[i];  sw[SW_WN_BE1 + i] = wn_be1[i];
    sw[SW_WN_B2 + i] = wn_b2[i];  sw[SW_WN_G2 + i] = wn_g2[i];  sw[SW_WN_BE2 + i] = wn_be2[i];
  }
  for (int i = t; i < 256;  i += 320) { sw[SW_WN_W1 + i] = wn_w1[i]; sw[SW_WN_W2 + i] = wn_w2[i]; }

  // ---- gather staging lambda (threads 0..255, one uint4 of bf16 each) ----
  auto stage = [&](int pp, int buf) {
    if (t < 256) {
      const int k  = t >> 4;
      const int c8 = (t & 15) * 8;
      const int n  = nbase + pp;
      const int idx = nei_inds[n * KNN + k];
      const float* src = sparse_feats + (long)idx * CIN + c8;
      const float4 va = *(const float4*)(src);
      const float4 vb = *(const float4*)(src + 4);
      unsigned short tmp[8];
      tmp[0] = f2bf(va.x); tmp[1] = f2bf(va.y); tmp[2] = f2bf(va.z); tmp[3] = f2bf(va.w);
      tmp[4] = f2bf(vb.x); tmp[5] = f2bf(vb.y); tmp[6] = f2bf(vb.z); tmp[7] = f2bf(vb.w);
      *(uint4*)(&feat_s[buf][k][c8]) = *(uint4*)tmp;
    }
  };

  stage(0, 0);      // overlap point-0 gather with the nets phase
  __syncthreads();  // weights visible

  // ---- nets phase: thread t<256 handles pair (p = t>>4, k = t&15) ----
  if (t < 256) {
    const int p  = t >> 4;
    const int kk = t & 15;
    const int n  = nbase + p;
    const int idx = nei_inds[n * KNN + kk];
    const float x0 = sparse_xyz[idx*3+0] - dense_xyz[n*3+0];
    const float x1 = sparse_xyz[idx*3+1] - dense_xyz[n*3+1];
    const float x2 = sparse_xyz[idx*3+2] - dense_xyz[n*3+2];

    // pe layer0 (3->32) + LN + act
    float h[32];
#pragma unroll
    for (int c = 0; c < 32; ++c)
      h[c] = x0*sw[SW_PE_W0+c] + x1*sw[SW_PE_W0+32+c] + x2*sw[SW_PE_W0+64+c] + sw[SW_PE_B0+c];
    ln_inlane<32>(h, &sw[SW_PE_G0], &sw[SW_PE_BE0], true);

    // pe layer1 (32->32) + LN (no act)
    float z[32];
#pragma unroll
    for (int c = 0; c < 32; ++c) z[c] = sw[SW_PE_B1 + c];
#pragma unroll 4
    for (int j = 0; j < 32; ++j) {
      const float hj = h[j];
#pragma unroll
      for (int c = 0; c < 32; ++c) z[c] += hj * sw[SW_PE_W1 + j*32 + c];
    }
    ln_inlane<32>(z, &sw[SW_PE_G1], &sw[SW_PE_BE1], false);
#pragma unroll
    for (int c = 0; c < 32; ++c) pe_s[p][kk][c] = f2bf(z[c]);

    // wn layer0 (3->16) + LN + act
    float w[16];
#pragma unroll
    for (int m = 0; m < 16; ++m)
      w[m] = x0*sw[SW_WN_W0+m] + x1*sw[SW_WN_W0+16+m] + x2*sw[SW_WN_W0+32+m] + sw[SW_WN_B0+m];
    ln_inlane<16>(w, &sw[SW_WN_G0], &sw[SW_WN_BE0], true);

    // wn layer1 (16->16) + LN + act
    float z2[16];
#pragma unroll
    for (int m = 0; m < 16; ++m) z2[m] = sw[SW_WN_B1 + m];
#pragma unroll 4
    for (int j = 0; j < 16; ++j) {
      const float wj = w[j];
#pragma unroll
      for (int m = 0; m < 16; ++m) z2[m] += wj * sw[SW_WN_W1 + j*16 + m];
    }
    ln_inlane<16>(z2, &sw[SW_WN_G1], &sw[SW_WN_BE1], true);

    // wn layer2 (16->16) + LN (no act)
#pragma unroll
    for (int m = 0; m < 16; ++m) w[m] = sw[SW_WN_B2 + m];
#pragma unroll 4
    for (int j = 0; j < 16; ++j) {
      const float wj = z2[j];
#pragma unroll
      for (int m = 0; m < 16; ++m) w[m] += wj * sw[SW_WN_W2 + j*16 + m];
    }
    ln_inlane<16>(w, &sw[SW_WN_G2], &sw[SW_WN_BE2], false);
#pragma unroll
    for (int m = 0; m < 16; ++m) wts_s[p][kk*16 + m] = w[m];
  }
  __syncthreads();  // nets + stage(0) complete

  // ---- einsum: thread = (chunk = t>>4 in 0..19, m = t&15) ----
  const int chunk = t >> 4;
  const int m     = t & 15;

#pragma unroll 1
  for (int pp = 0; pp < NPB; ++pp) {
    const int buf = pp & 1;
    if (pp + 1 < NPB) stage(pp + 1, buf ^ 1);   // overlap next gather

    float wkv[KNN];
#pragma unroll
    for (int k = 0; k < KNN; ++k) wkv[k] = wts_s[pp][k*16 + m];

    float acc[8];
#pragma unroll
    for (int j = 0; j < 8; ++j) acc[j] = 0.f;

    if (chunk < 16) {       // waves 0..3: sparse-feature channels
#pragma unroll
      for (int k = 0; k < KNN; ++k) {
        U16x8 f; f.u4 = *(const uint4*)(&feat_s[buf][k][chunk*8]);
        const float wv = wkv[k];
#pragma unroll
        for (int j = 0; j < 8; ++j) acc[j] += bf2f(f.us[j]) * wv;
      }
    } else {                // wave 4: pe channels
#pragma unroll
      for (int k = 0; k < KNN; ++k) {
        U16x8 f; f.u4 = *(const uint4*)(&pe_s[pp][k][(chunk-16)*8]);
        const float wv = wkv[k];
#pragma unroll
        for (int j = 0; j < 8; ++j) acc[j] += bf2f(f.us[j]) * wv;
      }
    }

    unsigned short ob[8];
#pragma unroll
    for (int j = 0; j < 8; ++j) ob[j] = f2bf(acc[j]);
    *(uint4*)(apack + (long)(nbase + pp) * KDIM + chunk*128 + m*8) = *(uint4*)ob;

    __syncthreads();
  }
}

// ============================================================================
// Kernel G: C[40000x128] = A[40000x2560] @ W, M=32/wave x N=64/wave register
// blocking (2 A-frags share 4 B-frags), 64 points/block, fused LN epilogue.
// ============================================================================
__global__ __launch_bounds__(256)
void pct_gemm64(
    const unsigned short* __restrict__ apack,
    const unsigned short* __restrict__ wpack,
    const float* __restrict__ lin_b, const float* __restrict__ lin_g,
    const float* __restrict__ lin_be, const float* __restrict__ dense_feats,
    float* __restrict__ out)
{
  __shared__ float out_s[64][132];

  const int t    = threadIdx.x;
  const int lane = t & 63;
  const int wave = t >> 6;
  const int mt   = wave >> 1;
  const int nh   = wave & 1;
  const int n0   = blockIdx.x * 64;

  const unsigned short* a0p = apack + (long)(n0 + mt*32 + (lane & 15)) * KDIM + ((lane >> 4) * 8);
  const unsigned short* a1p = a0p + (long)16 * KDIM;
  const unsigned short* wp0 = wpack + ((long)(nh*4) * 64 + lane) * 8;

  f32x4 acc[2][4];
#pragma unroll
  for (int at = 0; at < 2; ++at)
#pragma unroll
    for (int tt = 0; tt < 4; ++tt) acc[at][tt] = (f32x4){0.f, 0.f, 0.f, 0.f};

#pragma unroll 2
  for (int s = 0; s < 80; ++s) {
    U16x8 a0, a1;
    a0.u4 = *(const uint4*)(a0p + s*32);
    a1.u4 = *(const uint4*)(a1p + s*32);
    const unsigned short* wp = wp0 + (long)s * 4096;
    U16x8 b[4];
#pragma unroll
    for (int tt = 0; tt < 4; ++tt) b[tt].u4 = *(const uint4*)(wp + tt*512);
#pragma unroll
    for (int tt = 0; tt < 4; ++tt) {
      acc[0][tt] = __builtin_amdgcn_mfma_f32_16x16x32_bf16(a0.b, b[tt].b, acc[0][tt], 0, 0, 0);
      acc[1][tt] = __builtin_amdgcn_mfma_f32_16x16x32_bf16(a1.b, b[tt].b, acc[1][tt], 0, 0, 0);
    }
  }

  // scatter: row = mt*32 + at*16 + quad*4 + r, col = nh*64 + tt*16 + (lane&15)
  {
    const int colb = nh*64 + (lane & 15);
    const int quad = lane >> 4;
#pragma unroll
    for (int at = 0; at < 2; ++at) {
      const int row0 = mt*32 + at*16 + quad*4;
#pragma unroll
      for (int tt = 0; tt < 4; ++tt)
#pragma unroll
        for (int r = 0; r < 4; ++r)
          out_s[row0 + r][colb + tt*16] = acc[at][tt][r];
    }
  }
  __syncthreads();

  // epilogue: 4 threads/point, column-interleaved to dodge bank conflicts
  {
    const int p = t >> 2, q = t & 3;
    const int n = n0 + p;
    float v[32];
#pragma unroll
    for (int i = 0; i < 8; ++i) {
      const int cb = (i*4 + q) * 4;
      const float4 r  = *(const float4*)(&out_s[p][cb]);
      const float4 bb = *(const float4*)(lin_b + cb);
      v[i*4+0] = r.x + bb.x; v[i*4+1] = r.y + bb.y;
      v[i*4+2] = r.z + bb.z; v[i*4+3] = r.w + bb.w;
    }
    float sum = 0.f;
#pragma unroll
    for (int i = 0; i < 32; ++i) sum += v[i];
    const float mu = rsum4(sum) * (1.f/128.f);
    float qs = 0.f;
#pragma unroll
    for (int i = 0; i < 32; ++i) { float d = v[i] - mu; qs += d*d; }
    const float rs = rsqrtf(rsum4(qs) * (1.f/128.f) + LEPS);
#pragma unroll
    for (int i = 0; i < 8; ++i) {
      const int cb = (i*4 + q) * 4;
      const float4 g  = *(const float4*)(lin_g  + cb);
      const float4 be = *(const float4*)(lin_be + cb);
      const float4 df = *(const float4*)(dense_feats + (long)n*COUT + cb);
      float4 y;
      y.x = lrelu((v[i*4+0]-mu)*rs*g.x + be.x) + df.x;
      y.y = lrelu((v[i*4+1]-mu)*rs*g.y + be.y) + df.y;
      y.z = lrelu((v[i*4+2]-mu)*rs*g.z + be.z) + df.z;
      y.w = lrelu((v[i*4+3]-mu)*rs*g.w + be.w) + df.w;
      *(float4*)(out + (long)n*COUT + cb) = y;
    }
  }
}

// ============================================================================
// Fallback: round-2 fully-fused kernel (used if ws_size is too small)
// ============================================================================
__global__ __launch_bounds__(256)
void pct_fused(
    const float* __restrict__ sparse_xyz,
    const float* __restrict__ sparse_feats,
    const int* __restrict__ nei_inds,
    const float* __restrict__ dense_xyz,
    const float* __restrict__ dense_feats,
    const float* __restrict__ pe_w0, const float* __restrict__ pe_b0,
    const float* __restrict__ pe_g0, const float* __restrict__ pe_be0,
    const float* __restrict__ pe_w1, const float* __restrict__ pe_b1,
    const float* __restrict__ pe_g1, const float* __restrict__ pe_be1,
    const float* __restrict__ wn_w0, const float* __restrict__ wn_b0,
    const float* __restrict__ wn_g0, const float* __restrict__ wn_be0,
    const float* __restrict__ wn_w1, const float* __restrict__ wn_b1,
    const float* __restrict__ wn_g1, const float* __restrict__ wn_be1,
    const float* __restrict__ wn_w2, const float* __restrict__ wn_b2,
    const float* __restrict__ wn_g2, const float* __restrict__ wn_be2,
    const float* __restrict__ lin_w, const float* __restrict__ lin_b,
    const float* __restrict__ lin_g, const float* __restrict__ lin_be,
    float* __restrict__ out)
{
  __shared__ __align__(16) unsigned short feat_s[KNN][CF];
  __shared__ float wts_s[KNN][MM];
  __shared__ float loc_s[KNN][3];
  __shared__ int   nei_s[KNN];
  __shared__ __align__(16) unsigned short out_tile[CF*MM][8];

  const int t  = threadIdx.x;
  const int n0 = blockIdx.x * 8;
  const int k  = t >> 4;
  const int l  = t & 15;

#pragma unroll 1
  for (int p = 0; p < 8; ++p) {
    const int n = n0 + p;
    if (t < KNN) {
      int idx = nei_inds[n*KNN + t];
      nei_s[t] = idx;
      loc_s[t][0] = sparse_xyz[idx*3+0] - dense_xyz[n*3+0];
      loc_s[t][1] = sparse_xyz[idx*3+1] - dense_xyz[n*3+1];
      loc_s[t][2] = sparse_xyz[idx*3+2] - dense_xyz[n*3+2];
    }
    __syncthreads();
    {
      const int gk = t >> 4;
      const int c8 = (t & 15) * 8;
      const float* src = sparse_feats + (long)nei_s[gk]*CIN + c8;
      const float4 va = *(const float4*)(src);
      const float4 vb = *(const float4*)(src + 4);
      unsigned short* dst = &feat_s[gk][c8];
      dst[0] = f2bf(va.x); dst[1] = f2bf(va.y); dst[2] = f2bf(va.z); dst[3] = f2bf(va.w);
      dst[4] = f2bf(vb.x); dst[5] = f2bf(vb.y); dst[6] = f2bf(vb.z); dst[7] = f2bf(vb.w);
    }
    const float x0 = loc_s[k][0], x1 = loc_s[k][1], x2 = loc_s[k][2];
    const int c0 = l, c1 = l + 16;
    float ha = x0*pe_w0[0*PEC+c0] + x1*pe_w0[1*PEC+c0] + x2*pe_w0[2*PEC+c0] + pe_b0[c0];
    float hb = x0*pe_w0[0*PEC+c1] + x1*pe_w0[1*PEC+c1] + x2*pe_w0[2*PEC+c1] + pe_b0[c1];
    {
      float mu = rsum16(ha + hb) * (1.f/32.f);
      float da = ha - mu, db = hb - mu;
      float q  = rsum16(da*da + db*db);
      float rs = rsqrtf(q*(1.f/32.f) + LEPS);
      ha = lrelu(da*rs*pe_g0[c0] + pe_be0[c0]);
      hb = lrelu(db*rs*pe_g0[c1] + pe_be0[c1]);
    }
    float za = pe_b1[c0], zb = pe_b1[c1];
#pragma unroll
    for (int j = 0; j < 16; ++j) {
      float va = __shfl(ha, j, 16);
      float vb = __shfl(hb, j, 16);
      za += va * pe_w1[j*PEC + c0] + vb * pe_w1[(j+16)*PEC + c0];
      zb += va * pe_w1[j*PEC + c1] + vb * pe_w1[(j+16)*PEC + c1];
    }
    {
      float mu = rsum16(za + zb) * (1.f/32.f);
      float da = za - mu, db = zb - mu;
      float q  = rsum16(da*da + db*db);
      float rs = rsqrtf(q*(1.f/32.f) + LEPS);
      feat_s[k][CIN + c0] = f2bf(da*rs*pe_g1[c0] + pe_be1[c0]);
      feat_s[k][CIN + c1] = f2bf(db*rs*pe_g1[c1] + pe_be1[c1]);
    }
    float w0v = x0*wn_w0[0*MM+l] + x1*wn_w0[1*MM+l] + x2*wn_w0[2*MM+l] + wn_b0[l];
    {
      float mu = rsum16(w0v) * (1.f/16.f);
      float d  = w0v - mu;
      float rs = rsqrtf(rsum16(d*d)*(1.f/16.f) + LEPS);
      w0v = lrelu(d*rs*wn_g0[l] + wn_be0[l]);
    }
    float w1v = wn_b1[l];
#pragma unroll
    for (int j = 0; j < 16; ++j)
      w1v += __shfl(w0v, j, 16) * wn_w1[j*MM + l];
    {
      float mu = rsum16(w1v) * (1.f/16.f);
      float d  = w1v - mu;
      float rs = rsqrtf(rsum16(d*d)*(1.f/16.f) + LEPS);
      w1v = lrelu(d*rs*wn_g1[l] + wn_be1[l]);
    }
    float w2v = wn_b2[l];
#pragma unroll
    for (int j = 0; j < 16; ++j)
      w2v += __shfl(w1v, j, 16) * wn_w2[j*MM + l];
    {
      float mu = rsum16(w2v) * (1.f/16.f);
      float d  = w2v - mu;
      float rs = rsqrtf(rsum16(d*d)*(1.f/16.f) + LEPS);
      w2v = d*rs*wn_g2[l] + wn_be2[l];
    }
    wts_s[k][l] = w2v;
    __syncthreads();
    {
      const int m = t & 15;
      const int g = t >> 4;
      float wv[KNN];
#pragma unroll
      for (int kk = 0; kk < KNN; ++kk) wv[kk] = wts_s[kk][m];
#pragma unroll
      for (int j = 0; j < 10; ++j) {
        const int c = g*10 + j;
        float acc = 0.f;
#pragma unroll
        for (int kk = 0; kk < KNN; ++kk)
          acc += bf2f(feat_s[kk][c]) * wv[kk];
        out_tile[c*MM + m][p] = f2bf(acc);
      }
    }
    __syncthreads();
  }
  {
    const int h  = t >> 6;
    const int o0 = (t & 63) * 2;
    float acc0[8], acc1[8];
#pragma unroll
    for (int p = 0; p < 8; ++p) { acc0[p] = 0.f; acc1[p] = 0.f; }
    const int i0 = h * 640;
    for (int i = i0; i < i0 + 640; ++i) {
      const float2 wv = *(const float2*)(lin_w + (long)i*COUT + o0);
      const float wa = wv.x;
      const float wc = wv.y;
      const uint4 r = *(const uint4*)(&out_tile[i][0]);
      const float f0 = bf2f((unsigned short)(r.x & 0xffffu));
      const float f1 = bf2f((unsigned short)(r.x >> 16));
      const float g2 = bf2f((unsigned short)(r.y & 0xffffu));
      const float g3 = bf2f((unsigned short)(r.y >> 16));
      const float g4 = bf2f((unsigned short)(r.z & 0xffffu));
      const float g5 = bf2f((unsigned short)(r.z >> 16));
      const float g6 = bf2f((unsigned short)(r.w & 0xffffu));
      const float g7 = bf2f((unsigned short)(r.w >> 16));
      acc0[0] += f0*wa; acc1[0] += f0*wc;
      acc0[1] += f1*wa; acc1[1] += f1*wc;
      acc0[2] += g2*wa; acc1[2] += g2*wc;
      acc0[3] += g3*wa; acc1[3] += g3*wc;
      acc0[4] += g4*wa; acc1[4] += g4*wc;
      acc0[5] += g5*wa; acc1[5] += g5*wc;
      acc0[6] += g6*wa; acc1[6] += g6*wc;
      acc0[7] += g7*wa; acc1[7] += g7*wc;
    }
    __syncthreads();
    float* red = (float*)&out_tile[0][0];
#pragma unroll
    for (int p = 0; p < 8; ++p) {
      red[((h*8 + p) << 7) + o0    ] = acc0[p];
      red[((h*8 + p) << 7) + o0 + 1] = acc1[p];
    }
    __syncthreads();
    const int p2 = t >> 5, l2 = t & 31;
    const int n  = n0 + p2;
    float v[4];
#pragma unroll
    for (int j = 0; j < 4; ++j) {
      const int o = l2 + (j << 5);
      float sv = red[((0*8 + p2) << 7) + o] + red[((1*8 + p2) << 7) + o]
               + red[((2*8 + p2) << 7) + o] + red[((3*8 + p2) << 7) + o];
      v[j] = sv + lin_b[o];
    }
    float mu = rsum32(v[0] + v[1] + v[2] + v[3]) * (1.f/128.f);
    float q = 0.f;
#pragma unroll
    for (int j = 0; j < 4; ++j) { float d = v[j] - mu; q += d*d; }
    float rs = rsqrtf(rsum32(q) * (1.f/128.f) + LEPS);
#pragma unroll
    for (int j = 0; j < 4; ++j) {
      const int o = l2 + (j << 5);
      float y = (v[j] - mu) * rs * lin_g[o] + lin_be[o];
      y = lrelu(y);
      y += dense_feats[n*COUT + o];
      out[n*COUT + o] = y;
    }
  }
}

extern "C" void kernel_launch(void* const* d_in, const int* in_sizes, int n_in,
                              void* d_out, int out_size, void* d_ws, size_t ws_size,
                              hipStream_t stream) {
  const int Nd = in_sizes[2] / KNN;   // 40000
  const size_t a_bytes = (size_t)Nd * KDIM * 2;     // 204.8 MB
  const size_t w_bytes = (size_t)KDIM * COUT * 2;   // 655 KB
  const bool use_split = (ws_size >= a_bytes + w_bytes) && (Nd % 64 == 0);

  if (use_split) {
    unsigned short* apack = (unsigned short*)d_ws;
    unsigned short* wpack = (unsigned short*)((char*)d_ws + a_bytes);

    pct_pack_w<<<dim3((KDIM/32)*8*64/256), dim3(256), 0, stream>>>(
      (const float*)d_in[27], wpack);

    pct_einsum<<<dim3(Nd / NPB), dim3(320), 0, stream>>>(
      (const float*)d_in[0],  (const float*)d_in[1],  (const int*)d_in[2],
      (const float*)d_in[4],
      (const float*)d_in[7],  (const float*)d_in[8],  (const float*)d_in[9],  (const float*)d_in[10],
      (const float*)d_in[11], (const float*)d_in[12], (const float*)d_in[13], (const float*)d_in[14],
      (const float*)d_in[15], (const float*)d_in[16], (const float*)d_in[17], (const float*)d_in[18],
      (const float*)d_in[19], (const float*)d_in[20], (const float*)d_in[21], (const float*)d_in[22],
      (const float*)d_in[23], (const float*)d_in[24], (const float*)d_in[25], (const float*)d_in[26],
      apack);

    pct_gemm64<<<dim3(Nd / 64), dim3(256), 0, stream>>>(
      apack, wpack,
      (const float*)d_in[28], (const float*)d_in[29], (const float*)d_in[30],
      (const float*)d_in[6], (float*)d_out);
  } else {
    pct_fused<<<dim3(Nd / 8), dim3(256), 0, stream>>>(
      (const float*)d_in[0],  (const float*)d_in[1],  (const int*)d_in[2],
      (const float*)d_in[4],  (const float*)d_in[6],
      (const float*)d_in[7],  (const float*)d_in[8],  (const float*)d_in[9],  (const float*)d_in[10],
      (const float*)d_in[11], (const float*)d_in[12], (const float*)d_in[13], (const float*)d_in[14],
      (const float*)d_in[15], (const float*)d_in[16], (const float*)d_in[17], (const float*)d_in[18],
      (const float*)d_in[19], (const float*)d_in[20], (const float*)d_in[21], (const float*)d_in[22],
      (const float*)d_in[23], (const float*)d_in[24], (const float*)d_in[25], (const float*)d_in[26],
      (const float*)d_in[27], (const float*)d_in[28], (const float*)d_in[29], (const float*)d_in[30],
      (float*)d_out);
  }
}

// Round 5
// 481.974 us; speedup vs baseline: 2.0176x; 1.2183x over previous
//
#include <hip/hip_runtime.h>

#define NPB  16     // dense points per block (einsum kernel)
#define KNN  16     // neighbors
#define CIN  128
#define CF   160    // Cin + PE
#define MM   16     // weightnet out channels
#define PEC  32     // positional encoding channels
#define COUT 128
#define KDIM 2560   // CF * MM
#define LEPS 1e-5f

typedef __bf16 bf16x8 __attribute__((ext_vector_type(8)));
typedef float  f32x4  __attribute__((ext_vector_type(4)));
union U16x8 { uint4 u4; bf16x8 b; unsigned short us[8]; };

// LDS weight-bank offsets (floats)
#define SW_PE_W0   0
#define SW_PE_B0   96
#define SW_PE_G0   128
#define SW_PE_BE0  160
#define SW_PE_W1   192
#define SW_PE_B1   1216
#define SW_PE_G1   1248
#define SW_PE_BE1  1280
#define SW_WN_W0   1312
#define SW_WN_B0   1360
#define SW_WN_G0   1376
#define SW_WN_BE0  1392
#define SW_WN_W1   1408
#define SW_WN_B1   1664
#define SW_WN_G1   1680
#define SW_WN_BE1  1696
#define SW_WN_W2   1712
#define SW_WN_B2   1968
#define SW_WN_G2   1984
#define SW_WN_BE2  2000
#define SW_TOTAL   2016

__device__ __forceinline__ float bf2f(unsigned short b){
  union { unsigned int u; float f; } x; x.u = ((unsigned int)b) << 16; return x.f;
}
__device__ __forceinline__ unsigned short f2bf(float f){
  union { float f; unsigned int u; } x; x.f = f;
  unsigned int r = (x.u + 0x7fffu + ((x.u >> 16) & 1u)) >> 16;
  return (unsigned short)r;
}
__device__ __forceinline__ float rsum16(float v){
  v += __shfl_xor(v, 8, 16);
  v += __shfl_xor(v, 4, 16);
  v += __shfl_xor(v, 2, 16);
  v += __shfl_xor(v, 1, 16);
  return v;
}
__device__ __forceinline__ float rsum8(float v){
  v += __shfl_xor(v, 4, 8);
  v += __shfl_xor(v, 2, 8);
  v += __shfl_xor(v, 1, 8);
  return v;
}
__device__ __forceinline__ float rsum32(float v){
  v += __shfl_xor(v, 16, 32);
  v += __shfl_xor(v, 8, 32);
  v += __shfl_xor(v, 4, 32);
  v += __shfl_xor(v, 2, 32);
  v += __shfl_xor(v, 1, 32);
  return v;
}
__device__ __forceinline__ float lrelu(float v){ return v >= 0.f ? v : 0.1f * v; }

template<int N>
__device__ __forceinline__ void ln_inlane(float* v, const float* g, const float* be, bool act){
  float mu = 0.f;
#pragma unroll
  for (int i = 0; i < N; ++i) mu += v[i];
  mu *= (1.f / N);
  float var = 0.f;
#pragma unroll
  for (int i = 0; i < N; ++i) { float d = v[i] - mu; var += d * d; }
  const float rs = rsqrtf(var * (1.f / N) + LEPS);
#pragma unroll
  for (int i = 0; i < N; ++i) {
    float y = (v[i] - mu) * rs * g[i] + be[i];
    v[i] = act ? lrelu(y) : y;
  }
}

// ============================================================================
// Kernel P: pack lin_w (f32 [2560][128]) -> bf16 B-fragment layout for the
// permuted k-index i' = chunk*128 + m*8 + j  (c = chunk*8 + j, src row c*16+m).
// Fragment (s, tt, lane, j): i' = s*32 + (lane>>4)*8 + j, n = tt*16 + (lane&15)
// stored at wpack[((s*8 + tt)*64 + lane)*8 + j].
// ============================================================================
__global__ __launch_bounds__(256)
void pct_pack_w(const float* __restrict__ lin_w, unsigned short* __restrict__ wpack)
{
  const int u    = blockIdx.x * 256 + threadIdx.x;   // 0..40959
  const int lane = u & 63;
  const int tt   = (u >> 6) & 7;
  const int s    = u >> 9;
  const int ipb  = s * 32 + ((lane >> 4) * 8);
  const int nn   = tt * 16 + (lane & 15);
  unsigned short v[8];
#pragma unroll
  for (int j = 0; j < 8; ++j) {
    const int ip    = ipb + j;
    const int chunk = ip >> 7;
    const int rem   = ip & 127;
    const int m     = rem >> 3;
    const int jc    = rem & 7;
    const int srow  = (chunk * 8 + jc) * MM + m;    // lin_w row = c*16 + m
    v[j] = f2bf(lin_w[(long)srow * COUT + nn]);
  }
  *(uint4*)(wpack + (long)u * 8) = *(uint4*)v;
}

// ============================================================================
// Kernel E: per-thread small nets + barrier-free einsum reading feats from
// global (L2-resident). Block = 320 threads, 16 points. Only 2 barriers.
// apack[n][i'], i' = chunk*128 + m*8 + j.
// ============================================================================
__global__ __launch_bounds__(320)
void pct_einsum(
    const float* __restrict__ sparse_xyz,
    const float* __restrict__ sparse_feats,
    const int* __restrict__ nei_inds,
    const float* __restrict__ dense_xyz,
    const float* __restrict__ pe_w0, const float* __restrict__ pe_b0,
    const float* __restrict__ pe_g0, const float* __restrict__ pe_be0,
    const float* __restrict__ pe_w1, const float* __restrict__ pe_b1,
    const float* __restrict__ pe_g1, const float* __restrict__ pe_be1,
    const float* __restrict__ wn_w0, const float* __restrict__ wn_b0,
    const float* __restrict__ wn_g0, const float* __restrict__ wn_be0,
    const float* __restrict__ wn_w1, const float* __restrict__ wn_b1,
    const float* __restrict__ wn_g1, const float* __restrict__ wn_be1,
    const float* __restrict__ wn_w2, const float* __restrict__ wn_b2,
    const float* __restrict__ wn_g2, const float* __restrict__ wn_be2,
    unsigned short* __restrict__ apack)
{
  __shared__ float sw[SW_TOTAL];                               // 8064 B
  __shared__ __align__(16) unsigned short pe_s[NPB][KNN][PEC]; // 16384 B
  __shared__ float wts_s[NPB][MM*KNN];                         // 16384 B, [m*16+k]

  const int t     = threadIdx.x;
  const int nbase = blockIdx.x * NPB;

  // ---- stage weights in LDS ----
  for (int i = t; i < 96;   i += 320) sw[SW_PE_W0 + i] = pe_w0[i];
  for (int i = t; i < 32;   i += 320) {
    sw[SW_PE_B0 + i] = pe_b0[i];  sw[SW_PE_G0 + i] = pe_g0[i];  sw[SW_PE_BE0 + i] = pe_be0[i];
    sw[SW_PE_B1 + i] = pe_b1[i];  sw[SW_PE_G1 + i] = pe_g1[i];  sw[SW_PE_BE1 + i] = pe_be1[i];
  }
  for (int i = t; i < 1024; i += 320) sw[SW_PE_W1 + i] = pe_w1[i];
  for (int i = t; i < 48;   i += 320) sw[SW_WN_W0 + i] = wn_w0[i];
  for (int i = t; i < 16;   i += 320) {
    sw[SW_WN_B0 + i] = wn_b0[i];  sw[SW_WN_G0 + i] = wn_g0[i];  sw[SW_WN_BE0 + i] = wn_be0[i];
    sw[SW_WN_B1 + i] = wn_b1[i];  sw[SW_WN_G1 + i] = wn_g1[i];  sw[SW_WN_BE1 + i] = wn_be1[i];
    sw[SW_WN_B2 + i] = wn_b2[i];  sw[SW_WN_G2 + i] = wn_g2[i];  sw[SW_WN_BE2 + i] = wn_be2[i];
  }
  for (int i = t; i < 256;  i += 320) { sw[SW_WN_W1 + i] = wn_w1[i]; sw[SW_WN_W2 + i] = wn_w2[i]; }
  __syncthreads();

  // ---- nets phase: thread t<256 handles pair (p = t>>4, k = t&15) ----
  if (t < 256) {
    const int p  = t >> 4;
    const int kk = t & 15;
    const int n  = nbase + p;
    const int idx = nei_inds[n * KNN + kk];
    const float x0 = sparse_xyz[idx*3+0] - dense_xyz[n*3+0];
    const float x1 = sparse_xyz[idx*3+1] - dense_xyz[n*3+1];
    const float x2 = sparse_xyz[idx*3+2] - dense_xyz[n*3+2];

    // pe layer0 (3->32) + LN + act
    float h[32];
#pragma unroll
    for (int c = 0; c < 32; ++c)
      h[c] = x0*sw[SW_PE_W0+c] + x1*sw[SW_PE_W0+32+c] + x2*sw[SW_PE_W0+64+c] + sw[SW_PE_B0+c];
    ln_inlane<32>(h, &sw[SW_PE_G0], &sw[SW_PE_BE0], true);

    // pe layer1 (32->32) + LN (no act)
    float z[32];
#pragma unroll
    for (int c = 0; c < 32; ++c) z[c] = sw[SW_PE_B1 + c];
#pragma unroll 4
    for (int j = 0; j < 32; ++j) {
      const float hj = h[j];
#pragma unroll
      for (int c = 0; c < 32; ++c) z[c] += hj * sw[SW_PE_W1 + j*32 + c];
    }
    ln_inlane<32>(z, &sw[SW_PE_G1], &sw[SW_PE_BE1], false);
#pragma unroll
    for (int c = 0; c < 32; ++c) pe_s[p][kk][c] = f2bf(z[c]);

    // wn layer0 (3->16) + LN + act
    float w[16];
#pragma unroll
    for (int m = 0; m < 16; ++m)
      w[m] = x0*sw[SW_WN_W0+m] + x1*sw[SW_WN_W0+16+m] + x2*sw[SW_WN_W0+32+m] + sw[SW_WN_B0+m];
    ln_inlane<16>(w, &sw[SW_WN_G0], &sw[SW_WN_BE0], true);

    // wn layer1 (16->16) + LN + act
    float z2[16];
#pragma unroll
    for (int m = 0; m < 16; ++m) z2[m] = sw[SW_WN_B1 + m];
#pragma unroll 4
    for (int j = 0; j < 16; ++j) {
      const float wj = w[j];
#pragma unroll
      for (int m = 0; m < 16; ++m) z2[m] += wj * sw[SW_WN_W1 + j*16 + m];
    }
    ln_inlane<16>(z2, &sw[SW_WN_G1], &sw[SW_WN_BE1], true);

    // wn layer2 (16->16) + LN (no act)
#pragma unroll
    for (int m = 0; m < 16; ++m) w[m] = sw[SW_WN_B2 + m];
#pragma unroll 4
    for (int j = 0; j < 16; ++j) {
      const float wj = z2[j];
#pragma unroll
      for (int m = 0; m < 16; ++m) w[m] += wj * sw[SW_WN_W2 + j*16 + m];
    }
    ln_inlane<16>(w, &sw[SW_WN_G2], &sw[SW_WN_BE2], false);
    // transposed store: wts_s[p][m*16 + k] so einsum reads contiguous k
#pragma unroll
    for (int m = 0; m < 16; ++m) wts_s[p][m*KNN + kk] = w[m];
  }
  __syncthreads();  // nets complete; no more barriers

  // ---- einsum: thread = (chunk = t>>4 in 0..19, m = t&15), feats from L2 ----
  const int chunk = t >> 4;
  const int m     = t & 15;

#pragma unroll 1
  for (int pp = 0; pp < NPB; ++pp) {
    // neighbor indices: wave-uniform -> scalar loads
    const int* nidx = nei_inds + (long)(nbase + pp) * KNN;
    int idxs[KNN];
#pragma unroll
    for (int k = 0; k < KNN; ++k) idxs[k] = nidx[k];

    // this thread's 16 mixing weights (contiguous: 4x ds_read_b128)
    float wkv[KNN];
    {
      const float* wr = &wts_s[pp][m*KNN];
#pragma unroll
      for (int q = 0; q < 4; ++q) {
        const float4 wv = *(const float4*)(wr + q*4);
        wkv[q*4+0] = wv.x; wkv[q*4+1] = wv.y; wkv[q*4+2] = wv.z; wkv[q*4+3] = wv.w;
      }
    }

    float acc[8];
#pragma unroll
    for (int j = 0; j < 8; ++j) acc[j] = 0.f;

    if (chunk < 16) {       // waves 0..3: sparse-feature channels (global f32)
#pragma unroll
      for (int k = 0; k < KNN; ++k) {
        const float* src = sparse_feats + (long)idxs[k] * CIN + chunk*8;
        const float4 a = *(const float4*)(src);
        const float4 b = *(const float4*)(src + 4);
        const float wv = wkv[k];
        acc[0] += a.x*wv; acc[1] += a.y*wv; acc[2] += a.z*wv; acc[3] += a.w*wv;
        acc[4] += b.x*wv; acc[5] += b.y*wv; acc[6] += b.z*wv; acc[7] += b.w*wv;
      }
    } else {                // wave 4: pe channels from LDS
#pragma unroll
      for (int k = 0; k < KNN; ++k) {
        U16x8 f; f.u4 = *(const uint4*)(&pe_s[pp][k][(chunk-16)*8]);
        const float wv = wkv[k];
#pragma unroll
        for (int j = 0; j < 8; ++j) acc[j] += bf2f(f.us[j]) * wv;
      }
    }

    unsigned short ob[8];
#pragma unroll
    for (int j = 0; j < 8; ++j) ob[j] = f2bf(acc[j]);
    *(uint4*)(apack + (long)(nbase + pp) * KDIM + chunk*128 + m*8) = *(uint4*)ob;
  }
}

// ============================================================================
// Kernel G: C[40000x128] = A[40000x2560] @ W. 32 points/block (1250 blocks,
// ~20 waves/CU). Wave w: all 32 rows x n-tiles {2w,2w+1}; register prefetch.
// ============================================================================
__global__ __launch_bounds__(256)
void pct_gemm32(
    const unsigned short* __restrict__ apack,
    const unsigned short* __restrict__ wpack,
    const float* __restrict__ lin_b, const float* __restrict__ lin_g,
    const float* __restrict__ lin_be, const float* __restrict__ dense_feats,
    float* __restrict__ out)
{
  __shared__ float out_s[32][132];

  const int t    = threadIdx.x;
  const int lane = t & 63;
  const int wave = t >> 6;     // 0..3 -> n-tiles 2w, 2w+1
  const int n0   = blockIdx.x * 32;

  const unsigned short* arow0 = apack + (long)(n0 + (lane & 15)) * KDIM + ((lane >> 4) * 8);
  const unsigned short* arow1 = arow0 + (long)16 * KDIM;
  const unsigned short* wp0   = wpack + ((long)(wave*2) * 64 + lane) * 8;

  f32x4 acc00 = {0.f,0.f,0.f,0.f}, acc01 = {0.f,0.f,0.f,0.f};
  f32x4 acc10 = {0.f,0.f,0.f,0.f}, acc11 = {0.f,0.f,0.f,0.f};

  U16x8 a0, a1, b0, b1;
  a0.u4 = *(const uint4*)(arow0);
  a1.u4 = *(const uint4*)(arow1);
  b0.u4 = *(const uint4*)(wp0);
  b1.u4 = *(const uint4*)(wp0 + 512);

#pragma unroll 2
  for (int s = 0; s < 80; ++s) {
    U16x8 na0, na1, nb0, nb1;
    if (s + 1 < 80) {
      na0.u4 = *(const uint4*)(arow0 + (s+1)*32);
      na1.u4 = *(const uint4*)(arow1 + (s+1)*32);
      nb0.u4 = *(const uint4*)(wp0 + (long)(s+1)*4096);
      nb1.u4 = *(const uint4*)(wp0 + (long)(s+1)*4096 + 512);
    }
    acc00 = __builtin_amdgcn_mfma_f32_16x16x32_bf16(a0.b, b0.b, acc00, 0, 0, 0);
    acc01 = __builtin_amdgcn_mfma_f32_16x16x32_bf16(a0.b, b1.b, acc01, 0, 0, 0);
    acc10 = __builtin_amdgcn_mfma_f32_16x16x32_bf16(a1.b, b0.b, acc10, 0, 0, 0);
    acc11 = __builtin_amdgcn_mfma_f32_16x16x32_bf16(a1.b, b1.b, acc11, 0, 0, 0);
    a0 = na0; a1 = na1; b0 = nb0; b1 = nb1;
  }

  // scatter: row = at*16 + quad*4 + r, col = wave*32 + bt*16 + (lane&15)
  {
    const int quad = lane >> 4;
    const int colb = wave*32 + (lane & 15);
#pragma unroll
    for (int r = 0; r < 4; ++r) {
      out_s[     quad*4 + r][colb     ] = acc00[r];
      out_s[     quad*4 + r][colb + 16] = acc01[r];
      out_s[16 + quad*4 + r][colb     ] = acc10[r];
      out_s[16 + quad*4 + r][colb + 16] = acc11[r];
    }
  }
  __syncthreads();

  // epilogue: 8 threads/point, 16 cols each (column-interleaved)
  {
    const int p  = t >> 3;
    const int l8 = t & 7;
    const int n  = n0 + p;
    float v[16];
#pragma unroll
    for (int i = 0; i < 4; ++i) {
      const int cb = (i*8 + l8) * 4;
      const float4 r  = *(const float4*)(&out_s[p][cb]);
      const float4 bb = *(const float4*)(lin_b + cb);
      v[i*4+0] = r.x + bb.x; v[i*4+1] = r.y + bb.y;
      v[i*4+2] = r.z + bb.z; v[i*4+3] = r.w + bb.w;
    }
    float sum = 0.f;
#pragma unroll
    for (int i = 0; i < 16; ++i) sum += v[i];
    const float mu = rsum8(sum) * (1.f/128.f);
    float qs = 0.f;
#pragma unroll
    for (int i = 0; i < 16; ++i) { float d = v[i] - mu; qs += d*d; }
    const float rs = rsqrtf(rsum8(qs) * (1.f/128.f) + LEPS);
#pragma unroll
    for (int i = 0; i < 4; ++i) {
      const int cb = (i*8 + l8) * 4;
      const float4 g  = *(const float4*)(lin_g  + cb);
      const float4 be = *(const float4*)(lin_be + cb);
      const float4 df = *(const float4*)(dense_feats + (long)n*COUT + cb);
      float4 y;
      y.x = lrelu((v[i*4+0]-mu)*rs*g.x + be.x) + df.x;
      y.y = lrelu((v[i*4+1]-mu)*rs*g.y + be.y) + df.y;
      y.z = lrelu((v[i*4+2]-mu)*rs*g.z + be.z) + df.z;
      y.w = lrelu((v[i*4+3]-mu)*rs*g.w + be.w) + df.w;
      *(float4*)(out + (long)n*COUT + cb) = y;
    }
  }
}

// ============================================================================
// Fallback: round-2 fully-fused kernel (used if ws_size is too small)
// ============================================================================
__global__ __launch_bounds__(256)
void pct_fused(
    const float* __restrict__ sparse_xyz,
    const float* __restrict__ sparse_feats,
    const int* __restrict__ nei_inds,
    const float* __restrict__ dense_xyz,
    const float* __restrict__ dense_feats,
    const float* __restrict__ pe_w0, const float* __restrict__ pe_b0,
    const float* __restrict__ pe_g0, const float* __restrict__ pe_be0,
    const float* __restrict__ pe_w1, const float* __restrict__ pe_b1,
    const float* __restrict__ pe_g1, const float* __restrict__ pe_be1,
    const float* __restrict__ wn_w0, const float* __restrict__ wn_b0,
    const float* __restrict__ wn_g0, const float* __restrict__ wn_be0,
    const float* __restrict__ wn_w1, const float* __restrict__ wn_b1,
    const float* __restrict__ wn_g1, const float* __restrict__ wn_be1,
    const float* __restrict__ wn_w2, const float* __restrict__ wn_b2,
    const float* __restrict__ wn_g2, const float* __restrict__ wn_be2,
    const float* __restrict__ lin_w, const float* __restrict__ lin_b,
    const float* __restrict__ lin_g, const float* __restrict__ lin_be,
    float* __restrict__ out)
{
  __shared__ __align__(16) unsigned short feat_s[KNN][CF];
  __shared__ float wts_s[KNN][MM];
  __shared__ float loc_s[KNN][3];
  __shared__ int   nei_s[KNN];
  __shared__ __align__(16) unsigned short out_tile[CF*MM][8];

  const int t  = threadIdx.x;
  const int n0 = blockIdx.x * 8;
  const int k  = t >> 4;
  const int l  = t & 15;

#pragma unroll 1
  for (int p = 0; p < 8; ++p) {
    const int n = n0 + p;
    if (t < KNN) {
      int idx = nei_inds[n*KNN + t];
      nei_s[t] = idx;
      loc_s[t][0] = sparse_xyz[idx*3+0] - dense_xyz[n*3+0];
      loc_s[t][1] = sparse_xyz[idx*3+1] - dense_xyz[n*3+1];
      loc_s[t][2] = sparse_xyz[idx*3+2] - dense_xyz[n*3+2];
    }
    __syncthreads();
    {
      const int gk = t >> 4;
      const int c8 = (t & 15) * 8;
      const float* src = sparse_feats + (long)nei_s[gk]*CIN + c8;
      const float4 va = *(const float4*)(src);
      const float4 vb = *(const float4*)(src + 4);
      unsigned short* dst = &feat_s[gk][c8];
      dst[0] = f2bf(va.x); dst[1] = f2bf(va.y); dst[2] = f2bf(va.z); dst[3] = f2bf(va.w);
      dst[4] = f2bf(vb.x); dst[5] = f2bf(vb.y); dst[6] = f2bf(vb.z); dst[7] = f2bf(vb.w);
    }
    const float x0 = loc_s[k][0], x1 = loc_s[k][1], x2 = loc_s[k][2];
    const int c0 = l, c1 = l + 16;
    float ha = x0*pe_w0[0*PEC+c0] + x1*pe_w0[1*PEC+c0] + x2*pe_w0[2*PEC+c0] + pe_b0[c0];
    float hb = x0*pe_w0[0*PEC+c1] + x1*pe_w0[1*PEC+c1] + x2*pe_w0[2*PEC+c1] + pe_b0[c1];
    {
      float mu = rsum16(ha + hb) * (1.f/32.f);
      float da = ha - mu, db = hb - mu;
      float q  = rsum16(da*da + db*db);
      float rs = rsqrtf(q*(1.f/32.f) + LEPS);
      ha = lrelu(da*rs*pe_g0[c0] + pe_be0[c0]);
      hb = lrelu(db*rs*pe_g0[c1] + pe_be0[c1]);
    }
    float za = pe_b1[c0], zb = pe_b1[c1];
#pragma unroll
    for (int j = 0; j < 16; ++j) {
      float va = __shfl(ha, j, 16);
      float vb = __shfl(hb, j, 16);
      za += va * pe_w1[j*PEC + c0] + vb * pe_w1[(j+16)*PEC + c0];
      zb += va * pe_w1[j*PEC + c1] + vb * pe_w1[(j+16)*PEC + c1];
    }
    {
      float mu = rsum16(za + zb) * (1.f/32.f);
      float da = za - mu, db = zb - mu;
      float q  = rsum16(da*da + db*db);
      float rs = rsqrtf(q*(1.f/32.f) + LEPS);
      feat_s[k][CIN + c0] = f2bf(da*rs*pe_g1[c0] + pe_be1[c0]);
      feat_s[k][CIN + c1] = f2bf(db*rs*pe_g1[c1] + pe_be1[c1]);
    }
    float w0v = x0*wn_w0[0*MM+l] + x1*wn_w0[1*MM+l] + x2*wn_w0[2*MM+l] + wn_b0[l];
    {
      float mu = rsum16(w0v) * (1.f/16.f);
      float d  = w0v - mu;
      float rs = rsqrtf(rsum16(d*d)*(1.f/16.f) + LEPS);
      w0v = lrelu(d*rs*wn_g0[l] + wn_be0[l]);
    }
    float w1v = wn_b1[l];
#pragma unroll
    for (int j = 0; j < 16; ++j)
      w1v += __shfl(w0v, j, 16) * wn_w1[j*MM + l];
    {
      float mu = rsum16(w1v) * (1.f/16.f);
      float d  = w1v - mu;
      float rs = rsqrtf(rsum16(d*d)*(1.f/16.f) + LEPS);
      w1v = lrelu(d*rs*wn_g1[l] + wn_be1[l]);
    }
    float w2v = wn_b2[l];
#pragma unroll
    for (int j = 0; j < 16; ++j)
      w2v += __shfl(w1v, j, 16) * wn_w2[j*MM + l];
    {
      float mu = rsum16(w2v) * (1.f/16.f);
      float d  = w2v - mu;
      float rs = rsqrtf(rsum16(d*d)*(1.f/16.f) + LEPS);
      w2v = d*rs*wn_g2[l] + wn_be2[l];
    }
    wts_s[k][l] = w2v;
    __syncthreads();
    {
      const int m = t & 15;
      const int g = t >> 4;
      float wv[KNN];
#pragma unroll
      for (int kk = 0; kk < KNN; ++kk) wv[kk] = wts_s[kk][m];
#pragma unroll
      for (int j = 0; j < 10; ++j) {
        const int c = g*10 + j;
        float acc = 0.f;
#pragma unroll
        for (int kk = 0; kk < KNN; ++kk)
          acc += bf2f(feat_s[kk][c]) * wv[kk];
        out_tile[c*MM + m][p] = f2bf(acc);
      }
    }
    __syncthreads();
  }
  {
    const int h  = t >> 6;
    const int o0 = (t & 63) * 2;
    float acc0[8], acc1[8];
#pragma unroll
    for (int p = 0; p < 8; ++p) { acc0[p] = 0.f; acc1[p] = 0.f; }
    const int i0 = h * 640;
    for (int i = i0; i < i0 + 640; ++i) {
      const float2 wv = *(const float2*)(lin_w + (long)i*COUT + o0);
      const float wa = wv.x;
      const float wc = wv.y;
      const uint4 r = *(const uint4*)(&out_tile[i][0]);
      const float f0 = bf2f((unsigned short)(r.x & 0xffffu));
      const float f1 = bf2f((unsigned short)(r.x >> 16));
      const float g2 = bf2f((unsigned short)(r.y & 0xffffu));
      const float g3 = bf2f((unsigned short)(r.y >> 16));
      const float g4 = bf2f((unsigned short)(r.z & 0xffffu));
      const float g5 = bf2f((unsigned short)(r.z >> 16));
      const float g6 = bf2f((unsigned short)(r.w & 0xffffu));
      const float g7 = bf2f((unsigned short)(r.w >> 16));
      acc0[0] += f0*wa; acc1[0] += f0*wc;
      acc0[1] += f1*wa; acc1[1] += f1*wc;
      acc0[2] += g2*wa; acc1[2] += g2*wc;
      acc0[3] += g3*wa; acc1[3] += g3*wc;
      acc0[4] += g4*wa; acc1[4] += g4*wc;
      acc0[5] += g5*wa; acc1[5] += g5*wc;
      acc0[6] += g6*wa; acc1[6] += g6*wc;
      acc0[7] += g7*wa; acc1[7] += g7*wc;
    }
    __syncthreads();
    float* red = (float*)&out_tile[0][0];
#pragma unroll
    for (int p = 0; p < 8; ++p) {
      red[((h*8 + p) << 7) + o0    ] = acc0[p];
      red[((h*8 + p) << 7) + o0 + 1] = acc1[p];
    }
    __syncthreads();
    const int p2 = t >> 5, l2 = t & 31;
    const int n  = n0 + p2;
    float v[4];
#pragma unroll
    for (int j = 0; j < 4; ++j) {
      const int o = l2 + (j << 5);
      float sv = red[((0*8 + p2) << 7) + o] + red[((1*8 + p2) << 7) + o]
               + red[((2*8 + p2) << 7) + o] + red[((3*8 + p2) << 7) + o];
      v[j] = sv + lin_b[o];
    }
    float mu = rsum32(v[0] + v[1] + v[2] + v[3]) * (1.f/128.f);
    float q = 0.f;
#pragma unroll
    for (int j = 0; j < 4; ++j) { float d = v[j] - mu; q += d*d; }
    float rs = rsqrtf(rsum32(q) * (1.f/128.f) + LEPS);
#pragma unroll
    for (int j = 0; j < 4; ++j) {
      const int o = l2 + (j << 5);
      float y = (v[j] - mu) * rs * lin_g[o] + lin_be[o];
      y = lrelu(y);
      y += dense_feats[n*COUT + o];
      out[n*COUT + o] = y;
    }
  }
}

extern "C" void kernel_launch(void* const* d_in, const int* in_sizes, int n_in,
                              void* d_out, int out_size, void* d_ws, size_t ws_size,
                              hipStream_t stream) {
  const int Nd = in_sizes[2] / KNN;   // 40000
  const size_t a_bytes = (size_t)Nd * KDIM * 2;     // 204.8 MB
  const size_t w_bytes = (size_t)KDIM * COUT * 2;   // 655 KB
  const bool use_split = (ws_size >= a_bytes + w_bytes) && (Nd % 32 == 0);

  if (use_split) {
    unsigned short* apack = (unsigned short*)d_ws;
    unsigned short* wpack = (unsigned short*)((char*)d_ws + a_bytes);

    pct_pack_w<<<dim3((KDIM/32)*8*64/256), dim3(256), 0, stream>>>(
      (const float*)d_in[27], wpack);

    pct_einsum<<<dim3(Nd / NPB), dim3(320), 0, stream>>>(
      (const float*)d_in[0],  (const float*)d_in[1],  (const int*)d_in[2],
      (const float*)d_in[4],
      (const float*)d_in[7],  (const float*)d_in[8],  (const float*)d_in[9],  (const float*)d_in[10],
      (const float*)d_in[11], (const float*)d_in[12], (const float*)d_in[13], (const float*)d_in[14],
      (const float*)d_in[15], (const float*)d_in[16], (const float*)d_in[17], (const float*)d_in[18],
      (const float*)d_in[19], (const float*)d_in[20], (const float*)d_in[21], (const float*)d_in[22],
      (const float*)d_in[23], (const float*)d_in[24], (const float*)d_in[25], (const float*)d_in[26],
      apack);

    pct_gemm32<<<dim3(Nd / 32), dim3(256), 0, stream>>>(
      apack, wpack,
      (const float*)d_in[28], (const float*)d_in[29], (const float*)d_in[30],
      (const float*)d_in[6], (float*)d_out);
  } else {
    pct_fused<<<dim3(Nd / 8), dim3(256), 0, stream>>>(
      (const float*)d_in[0],  (const float*)d_in[1],  (const int*)d_in[2],
      (const float*)d_in[4],  (const float*)d_in[6],
      (const float*)d_in[7],  (const float*)d_in[8],  (const float*)d_in[9],  (const float*)d_in[10],
      (const float*)d_in[11], (const float*)d_in[12], (const float*)d_in[13], (const float*)d_in[14],
      (const float*)d_in[15], (const float*)d_in[16], (const float*)d_in[17], (const float*)d_in[18],
      (const float*)d_in[19], (const float*)d_in[20], (const float*)d_in[21], (const float*)d_in[22],
      (const float*)d_in[23], (const float*)d_in[24], (const float*)d_in[25], (const float*)d_in[26],
      (const float*)d_in[27], (const float*)d_in[28], (const float*)d_in[29], (const float*)d_in[30],
      (float*)d_out);
  }
}